// Round 17
// baseline (230.507 us; speedup 1.0000x reference)
//
#include <hip/hip_runtime.h>
#include <math.h>

#define N_NODES 20000
#define N_EDGES 320000
#define EP (N_EDGES + N_NODES)   // with self loops
#define HEADS 5

typedef __attribute__((ext_vector_type(8))) __bf16 bf16x8;
typedef __attribute__((ext_vector_type(4))) float f32x4;

__device__ __forceinline__ float lrelu(float s) { return (s > 0.f) ? s : 0.2f * s; }

// fp32 -> bf16 bits, round-to-nearest-even
__device__ __forceinline__ unsigned f2bf(float f) {
  unsigned u = __float_as_uint(f);
  return (u + 0x7fffu + ((u >> 16) & 1u)) >> 16;
}

// ---------------- CSR build ----------------
__global__ void count_deg_k(const int* __restrict__ ei, int* __restrict__ deg) {
  int e = blockIdx.x * blockDim.x + threadIdx.x;
  if (e >= EP) return;
  int dst = (e < N_EDGES) ? ei[N_EDGES + e] : (e - N_EDGES);
  atomicAdd(&deg[dst], 1);
}

__global__ __launch_bounds__(256) void scan1_k(const int* __restrict__ deg,
                                               int* __restrict__ offs,
                                               int* __restrict__ bsum) {
  __shared__ int buf[256];
  int tid = threadIdx.x, i = blockIdx.x * 256 + tid;
  int v = (i < N_NODES) ? deg[i] : 0;
  buf[tid] = v;
  __syncthreads();
  for (int o = 1; o < 256; o <<= 1) {
    int t = (tid >= o) ? buf[tid - o] : 0;
    __syncthreads();
    buf[tid] += t;
    __syncthreads();
  }
  if (i < N_NODES) offs[i] = buf[tid] - v;   // block-local exclusive
  if (tid == 255) bsum[blockIdx.x] = buf[255];
}

__global__ __launch_bounds__(128) void scan2_k(int* __restrict__ bsum, int nb) {
  __shared__ int buf[128];
  int tid = threadIdx.x;
  int v = (tid < nb) ? bsum[tid] : 0;
  buf[tid] = v;
  __syncthreads();
  for (int o = 1; o < 128; o <<= 1) {
    int t = (tid >= o) ? buf[tid - o] : 0;
    __syncthreads();
    buf[tid] += t;
    __syncthreads();
  }
  if (tid < nb) bsum[tid] = buf[tid] - v;    // exclusive
}

__global__ void scan3_k(int* __restrict__ offs, const int* __restrict__ bsum) {
  int i = blockIdx.x * 256 + threadIdx.x;
  if (i < N_NODES) offs[i] += bsum[blockIdx.x];
  if (i == 0) offs[N_NODES] = EP;
}

__global__ void scatter_k(const int* __restrict__ ei, const int* __restrict__ offs,
                          int* __restrict__ cursor, int* __restrict__ ssrc) {
  int e = blockIdx.x * blockDim.x + threadIdx.x;
  if (e >= EP) return;
  int src, dst;
  if (e < N_EDGES) { src = ei[e]; dst = ei[N_EDGES + e]; }
  else             { src = e - N_EDGES; dst = src; }
  int pos = atomicAdd(&cursor[dst], 1);
  ssrc[offs[dst] + pos] = src;
}

// ---------------- fp32 -> bf16 convert (elementwise, float4 -> uint2) ----------------
__global__ __launch_bounds__(256) void conv_bf16_k(const float4* __restrict__ src,
                                                   uint2* __restrict__ dst, int n4) {
  int t = blockIdx.x * blockDim.x + threadIdx.x;
  if (t >= n4) return;
  float4 v = src[t];
  unsigned p0 = f2bf(v.x) | (f2bf(v.y) << 16);
  unsigned p1 = f2bf(v.z) | (f2bf(v.w) << 16);
  dst[t] = make_uint2(p0, p1);
}

// ---------------- pack W1[256][320] -> MFMA B-fragment order, bf16 ----------------
__global__ void packW1_k(const float* __restrict__ W, unsigned short* __restrict__ Wp) {
  int t = blockIdx.x * blockDim.x + threadIdx.x;
  if (t >= 256 * 320) return;
  int k = t / 320, n = t % 320;
  int gnt = n >> 4, ll = n & 15;
  int ks = k >> 5, kr = k & 31;
  int lh = kr >> 3, i = kr & 7;
  Wp[(((size_t)gnt * 8 + ks) * 64 + lh * 16 + ll) * 8 + i] = (unsigned short)f2bf(W[t]);
}

// ---------------- pack [W2|W3] (64x320 combined) -> fragment order, bf16 ----------------
__global__ void packW23_k(const float* __restrict__ W2, const float* __restrict__ W3,
                          unsigned short* __restrict__ Wp) {
  int t = blockIdx.x * blockDim.x + threadIdx.x;
  if (t >= 64 * 320) return;
  int k = t / 320, n = t % 320;
  int u = n / 32, c = n % 32;
  float val = (u < HEADS) ? W2[k * 160 + u * 32 + c] : W3[k * 160 + (u - HEADS) * 32 + c];
  int gnt = n >> 4, ll = n & 15;
  int ks = k >> 5, kr = k & 31;
  int lh = kr >> 3, i = kr & 7;
  Wp[(((size_t)gnt * 2 + ks) * 64 + lh * 16 + ll) * 8 + i] = (unsigned short)f2bf(val);
}

// ---------------- MFMA GEMM (bf16 in, fp32 acc) + fused att-sums ----------------
// Grid (5, 313) panel-fast. Block = 64 rows x 64 cols, 4 waves, no LDS/barriers.
template <int KSTEPS, int CH>
__global__ __launch_bounds__(256) void mfma_gemm_k(
    const unsigned short* __restrict__ A, const unsigned short* __restrict__ Bp,
    unsigned short* __restrict__ Cb,
    const float* __restrict__ attAs, const float* __restrict__ attAd,
    const float* __restrict__ attBs, const float* __restrict__ attBd,
    float* __restrict__ as_out, float* __restrict__ ad_out, int M) {
  constexpr int K = KSTEPS * 32;
  int panel = blockIdx.x;
  int bm = blockIdx.y * 64;
  int w = threadIdx.x >> 6;
  int l = threadIdx.x & 63;
  int ll = l & 15, lh = l >> 4;

  int arow = bm + w * 16 + ll;
  if (arow >= M) arow = M - 1;          // clamp; writes are guarded
  const unsigned short* ap = A + (size_t)arow * K + lh * 8;

  f32x4 acc[4] = {};
  for (int ks = 0; ks < KSTEPS; ks++) {
    bf16x8 af = *(const bf16x8*)(ap + ks * 32);
#pragma unroll
    for (int nt = 0; nt < 4; nt++) {
      bf16x8 bf = *(const bf16x8*)(Bp + (((size_t)(panel * 4 + nt) * KSTEPS + ks) * 64 + l) * 8);
      acc[nt] = __builtin_amdgcn_mfma_f32_16x16x32_bf16(af, bf, acc[nt], 0, 0, 0);
    }
  }

  int row0 = bm + w * 16 + lh * 4;
#pragma unroll
  for (int j = 0; j < 4; j++) {
    int r = row0 + j;
    if (r < M) {
#pragma unroll
      for (int nt = 0; nt < 4; nt++)
        Cb[((size_t)panel * M + r) * 64 + nt * 16 + ll] = (unsigned short)f2bf(acc[nt][j]);
    }
  }

  float ws[4], wd[4];
  if (CH == 64) {
#pragma unroll
    for (int nt = 0; nt < 4; nt++) {
      ws[nt] = attAs[panel * 64 + nt * 16 + ll];
      wd[nt] = attAd[panel * 64 + nt * 16 + ll];
    }
  } else {
#pragma unroll
    for (int nt = 0; nt < 4; nt++) {
      int u = panel * 2 + (nt >> 1);
      int c = (nt & 1) * 16 + ll;
      const float* s = (u < HEADS) ? attAs + u * 32 : attBs + (u - HEADS) * 32;
      const float* d = (u < HEADS) ? attAd + u * 32 : attBd + (u - HEADS) * 32;
      ws[nt] = s[c]; wd[nt] = d[c];
    }
  }
#pragma unroll
  for (int j = 0; j < 4; j++) {
    int r = row0 + j;
    if (CH == 64) {
      float ps = acc[0][j] * ws[0] + acc[1][j] * ws[1] + acc[2][j] * ws[2] + acc[3][j] * ws[3];
      float pd = acc[0][j] * wd[0] + acc[1][j] * wd[1] + acc[2][j] * wd[2] + acc[3][j] * wd[3];
#pragma unroll
      for (int o = 1; o < 16; o <<= 1) {
        ps += __shfl_xor(ps, o);
        pd += __shfl_xor(pd, o);
      }
      if (ll == 0 && r < M) {
        as_out[(size_t)panel * M + r] = ps;
        ad_out[(size_t)panel * M + r] = pd;
      }
    } else {
      float ls = acc[0][j] * ws[0] + acc[1][j] * ws[1];
      float ld = acc[0][j] * wd[0] + acc[1][j] * wd[1];
      float hs = acc[2][j] * ws[2] + acc[3][j] * ws[3];
      float hd = acc[2][j] * wd[2] + acc[3][j] * wd[3];
#pragma unroll
      for (int o = 1; o < 16; o <<= 1) {
        ls += __shfl_xor(ls, o); ld += __shfl_xor(ld, o);
        hs += __shfl_xor(hs, o); hd += __shfl_xor(hd, o);
      }
      if (ll == 0 && r < M) {
        int ulo = panel * 2, uhi = panel * 2 + 1;
        as_out[(size_t)ulo * M + r] = ls;  ad_out[(size_t)ulo * M + r] = ld;
        as_out[(size_t)uhi * M + r] = hs;  ad_out[(size_t)uhi * M + r] = hd;
      }
    }
  }
}

// bf16-quad load helper: uint2 -> 4 floats
__device__ __forceinline__ void bf4(uint2 v, float& f0, float& f1, float& f2, float& f3) {
  f0 = __uint_as_float(v.x << 16);
  f1 = __uint_as_float(v.x & 0xffff0000u);
  f2 = __uint_as_float(v.y << 16);
  f3 = __uint_as_float(v.y & 0xffff0000u);
}

// ---------------- layer 1: TWO nodes per block (10 waves), wave = (node-sub, head) ----------------
// R16 lesson: grid-stride serialized nodes via per-node barriers (-25%). This
// keeps the R15 per-wave body byte-identical but halves dispatch count with
// two INDEPENDENT node-groups per block and a single shared barrier.
// Wave-uniform guards; all-lane shuffles (inactive-source ds_bpermute
// undefined on CDNA — R3-R5 bug).
__global__ __launch_bounds__(640) void agg1_k(const int* __restrict__ offs,
                                              const int* __restrict__ ssrc,
                                              const float* __restrict__ a_s,
                                              const float* __restrict__ a_d,
                                              const uint2* __restrict__ xwb,
                                              const float* __restrict__ b1,
                                              unsigned short* __restrict__ h1b) {
  int wv = threadIdx.x >> 6;          // 0..9
  int sub = wv / HEADS;               // node sub-group 0/1
  int u = wv % HEADS;                 // head
  int lane = threadIdx.x & 63;
  int n = blockIdx.x * 2 + sub;
  int off = offs[n], end = offs[n + 1];
  int deg = end - off;
  float ad = a_d[(size_t)u * N_NODES + n];
  const float* asl = a_s + (size_t)u * N_NODES;
  const uint2* xb  = xwb + (size_t)u * N_NODES * 16;
  int g = lane >> 4, q = lane & 15;
  float ax = 0.f, ay = 0.f, az = 0.f, aw = 0.f;

  if (deg <= 64) {
    int s = 0;
    float e = -1e30f;
    if (lane < deg) { s = ssrc[off + lane]; e = lrelu(asl[s] + ad); }
    float m = e;
#pragma unroll
    for (int o = 32; o > 0; o >>= 1) m = fmaxf(m, __shfl_xor(m, o));
    float p = (lane < deg) ? __expf(e - m) : 0.f;
    float den = p;
#pragma unroll
    for (int o = 32; o > 0; o >>= 1) den += __shfl_xor(den, o);
    float alpha = p * (1.f / (den + 1e-16f));

    for (int base = 0; base < deg; base += 16) {
      float alv[4];
      uint2 v[4];
#pragma unroll
      for (int t = 0; t < 4; t++) {
        int b4 = base + t * 4;
        if (b4 < deg) {                       // wave-uniform guard
          int ee = b4 + g;
          bool ok = ee < deg;
          int es = ok ? ee : 0;               // lane 0 always valid (self-loop)
          float alr = __shfl(alpha, es);      // all lanes of taken branch
          int   sv  = __shfl(s, es);
          alv[t] = ok ? alr : 0.f;
          v[t] = xb[(size_t)sv * 16 + q];
        }
      }
#pragma unroll
      for (int t = 0; t < 4; t++) {
        if (base + t * 4 < deg) {
          float f0, f1, f2, f3;
          bf4(v[t], f0, f1, f2, f3);
          ax += alv[t] * f0; ay += alv[t] * f1;
          az += alv[t] * f2; aw += alv[t] * f3;
        }
      }
    }
  } else {
    float m = -1e30f;
    for (int i = off + lane; i < end; i += 64) m = fmaxf(m, lrelu(asl[ssrc[i]] + ad));
#pragma unroll
    for (int o = 32; o > 0; o >>= 1) m = fmaxf(m, __shfl_xor(m, o));
    float den = 0.f;
    for (int i = off + lane; i < end; i += 64) den += __expf(lrelu(asl[ssrc[i]] + ad) - m);
#pragma unroll
    for (int o = 32; o > 0; o >>= 1) den += __shfl_xor(den, o);
    float inv = 1.f / (den + 1e-16f);
    for (int base = off; base < end; base += 4) {
      int e = base + g;
      if (e < end) {
        int sv = ssrc[e];
        float al = __expf(lrelu(asl[sv] + ad) - m) * inv;
        float f0, f1, f2, f3;
        bf4(xb[(size_t)sv * 16 + q], f0, f1, f2, f3);
        ax += al * f0; ay += al * f1; az += al * f2; aw += al * f3;
      }
    }
  }

#pragma unroll
  for (int o = 16; o < 64; o <<= 1) {
    ax += __shfl_xor(ax, o); ay += __shfl_xor(ay, o);
    az += __shfl_xor(az, o); aw += __shfl_xor(aw, o);
  }

  __shared__ float sacc[2][HEADS][64];
  if (g == 0) *(float4*)&sacc[sub][u][q * 4] = make_float4(ax, ay, az, aw);
  __syncthreads();
  // wave 0 finalizes node sub0, wave 5 finalizes node sub1
  if (u == 0) {
    int t = lane;
    float v = sacc[sub][0][t] + sacc[sub][1][t] + sacc[sub][2][t] +
              sacc[sub][3][t] + sacc[sub][4][t];
    v = fmaxf(v * 0.2f + b1[t], 0.f);
    h1b[(size_t)n * 64 + t] = (unsigned short)f2bf(v);
  }
}

// ---------------- layers 2+3: TWO nodes per block (10 waves), wave = (sub, pair) ----------------
__global__ __launch_bounds__(640) void agg23_k(const int* __restrict__ offs,
                                               const int* __restrict__ ssrc,
                                               const float* __restrict__ a_s,
                                               const float* __restrict__ a_d,
                                               const uint2* __restrict__ xwb,
                                               const float* __restrict__ b2,
                                               const float* __restrict__ b3,
                                               float* __restrict__ z_out,
                                               float* __restrict__ mu_out,
                                               float* __restrict__ lv_out) {
  int wv = threadIdx.x >> 6;
  int sub = wv / HEADS;
  int gp = wv % HEADS;
  int lane = threadIdx.x & 63;
  int n = blockIdx.x * 2 + sub;
  int ulo = 2 * gp, uhi = 2 * gp + 1;
  int off = offs[n], end = offs[n + 1];
  int deg = end - off;
  float adlo = a_d[(size_t)ulo * N_NODES + n];
  float adhi = a_d[(size_t)uhi * N_NODES + n];
  const float* aslo = a_s + (size_t)ulo * N_NODES;
  const float* ashi = a_s + (size_t)uhi * N_NODES;
  const uint2* xb   = xwb + (size_t)gp * N_NODES * 16;
  int g = lane >> 4, q = lane & 15;
  float ax = 0.f, ay = 0.f, az = 0.f, aw = 0.f;

  if (deg <= 64) {
    int s = 0;
    float elo = -1e30f, ehi = -1e30f;
    if (lane < deg) {
      s = ssrc[off + lane];
      elo = lrelu(aslo[s] + adlo);
      ehi = lrelu(ashi[s] + adhi);
    }
    float mlo = elo, mhi = ehi;
#pragma unroll
    for (int o = 32; o > 0; o >>= 1) {
      mlo = fmaxf(mlo, __shfl_xor(mlo, o));
      mhi = fmaxf(mhi, __shfl_xor(mhi, o));
    }
    float plo = (lane < deg) ? __expf(elo - mlo) : 0.f;
    float phi = (lane < deg) ? __expf(ehi - mhi) : 0.f;
    float dlo = plo, dhi = phi;
#pragma unroll
    for (int o = 32; o > 0; o >>= 1) {
      dlo += __shfl_xor(dlo, o);
      dhi += __shfl_xor(dhi, o);
    }
    float allo = plo * (1.f / (dlo + 1e-16f));
    float alhi = phi * (1.f / (dhi + 1e-16f));

    for (int base = 0; base < deg; base += 16) {
      float alv[4];
      uint2 v[4];
#pragma unroll
      for (int t = 0; t < 4; t++) {
        int b4 = base + t * 4;
        if (b4 < deg) {                       // wave-uniform guard
          int ee = b4 + g;
          bool ok = ee < deg;
          int es = ok ? ee : 0;
          float a1 = __shfl(allo, es);        // all lanes of taken branch
          float a2 = __shfl(alhi, es);
          int   sv = __shfl(s, es);
          float alr = (q < 8) ? a1 : a2;
          alv[t] = ok ? alr : 0.f;
          v[t] = xb[(size_t)sv * 16 + q];
        }
      }
#pragma unroll
      for (int t = 0; t < 4; t++) {
        if (base + t * 4 < deg) {
          float f0, f1, f2, f3;
          bf4(v[t], f0, f1, f2, f3);
          ax += alv[t] * f0; ay += alv[t] * f1;
          az += alv[t] * f2; aw += alv[t] * f3;
        }
      }
    }
  } else {
    float mlo = -1e30f, mhi = -1e30f;
    for (int i = off + lane; i < end; i += 64) {
      int sv = ssrc[i];
      mlo = fmaxf(mlo, lrelu(aslo[sv] + adlo));
      mhi = fmaxf(mhi, lrelu(ashi[sv] + adhi));
    }
#pragma unroll
    for (int o = 32; o > 0; o >>= 1) {
      mlo = fmaxf(mlo, __shfl_xor(mlo, o));
      mhi = fmaxf(mhi, __shfl_xor(mhi, o));
    }
    float dlo = 0.f, dhi = 0.f;
    for (int i = off + lane; i < end; i += 64) {
      int sv = ssrc[i];
      dlo += __expf(lrelu(aslo[sv] + adlo) - mlo);
      dhi += __expf(lrelu(ashi[sv] + adhi) - mhi);
    }
#pragma unroll
    for (int o = 32; o > 0; o >>= 1) {
      dlo += __shfl_xor(dlo, o);
      dhi += __shfl_xor(dhi, o);
    }
    float ilo = 1.f / (dlo + 1e-16f), ihi = 1.f / (dhi + 1e-16f);
    for (int base = off; base < end; base += 4) {
      int e = base + g;
      if (e < end) {
        int sv = ssrc[e];
        float al;
        if (q < 8) al = __expf(lrelu(aslo[sv] + adlo) - mlo) * ilo;
        else       al = __expf(lrelu(ashi[sv] + adhi) - mhi) * ihi;
        float f0, f1, f2, f3;
        bf4(xb[(size_t)sv * 16 + q], f0, f1, f2, f3);
        ax += al * f0; ay += al * f1; az += al * f2; aw += al * f3;
      }
    }
  }

#pragma unroll
  for (int o = 16; o < 64; o <<= 1) {
    ax += __shfl_xor(ax, o); ay += __shfl_xor(ay, o);
    az += __shfl_xor(az, o); aw += __shfl_xor(aw, o);
  }

  __shared__ float sacc[2][HEADS][2][32];
  if (g == 0)
    *(float4*)&sacc[sub][gp][q >> 3][(q & 7) * 4] = make_float4(ax, ay, az, aw);
  __syncthreads();
  // wave 0 finalizes node sub0, wave 5 finalizes node sub1
  if (gp == 0) {
    int t = lane;
    if (t < 32) {
      float v = sacc[sub][0][0][t] + sacc[sub][0][1][t] + sacc[sub][1][0][t] +
                sacc[sub][1][1][t] + sacc[sub][2][0][t];
      v = v * 0.2f + b2[t];
      z_out[(size_t)n * 32 + t]  = v;
      mu_out[(size_t)n * 32 + t] = v;
    } else {
      int c = t - 32;
      float v = sacc[sub][2][1][c] + sacc[sub][3][0][c] + sacc[sub][3][1][c] +
                sacc[sub][4][0][c] + sacc[sub][4][1][c];
      v = v * 0.2f + b3[c];
      lv_out[(size_t)n * 32 + c] = v;
    }
  }
}

// ---------------- launch ----------------
extern "C" void kernel_launch(void* const* d_in, const int* in_sizes, int n_in,
                              void* d_out, int out_size, void* d_ws, size_t ws_size,
                              hipStream_t stream) {
  const float* x        = (const float*)d_in[0];
  const int*   ei       = (const int*)d_in[1];
  const float* W1       = (const float*)d_in[2];
  const float* att_src1 = (const float*)d_in[3];
  const float* att_dst1 = (const float*)d_in[4];
  const float* b1       = (const float*)d_in[5];
  const float* W2       = (const float*)d_in[6];
  const float* att_src2 = (const float*)d_in[7];
  const float* att_dst2 = (const float*)d_in[8];
  const float* b2       = (const float*)d_in[9];
  const float* W3       = (const float*)d_in[10];
  const float* att_src3 = (const float*)d_in[11];
  const float* att_dst3 = (const float*)d_in[12];
  const float* b3       = (const float*)d_in[13];
  float* out = (float*)d_out;

  char* w = (char*)d_ws;
  auto alloc = [&](size_t bytes) -> void* {
    void* p = (void*)w;
    w += (bytes + 255) & ~(size_t)255;
    return p;
  };
  int*            deg    = (int*)alloc((size_t)N_NODES * 4);
  int*            offs   = (int*)alloc((size_t)(N_NODES + 1) * 4);
  int*            cursor = (int*)alloc((size_t)N_NODES * 4);
  int*            bsum   = (int*)alloc((size_t)128 * 4);
  int*            ssrc   = (int*)alloc((size_t)EP * 4);
  unsigned short* xwb    = (unsigned short*)alloc((size_t)N_NODES * 320 * 2);  // 12.8 MB
  float*          a_s    = (float*)alloc((size_t)N_NODES * 10 * 4);
  float*          a_d    = (float*)alloc((size_t)N_NODES * 10 * 4);
  unsigned short* h1b    = (unsigned short*)alloc((size_t)N_NODES * 64 * 2);   // 2.56 MB
  unsigned short* xbf    = (unsigned short*)alloc((size_t)N_NODES * 256 * 2);  // 10.24 MB
  unsigned short* Wp1    = (unsigned short*)alloc((size_t)256 * 320 * 2);
  unsigned short* Wp23   = (unsigned short*)alloc((size_t)64 * 320 * 2);
  // total ~29 MB (< proven ~34 MB)

  hipMemsetAsync(deg, 0, (size_t)N_NODES * 4, stream);
  hipMemsetAsync(cursor, 0, (size_t)N_NODES * 4, stream);

  int eb = (EP + 255) / 256;
  int nb = (N_NODES + 255) / 256;   // 79
  count_deg_k<<<eb, 256, 0, stream>>>(ei, deg);
  scan1_k<<<nb, 256, 0, stream>>>(deg, offs, bsum);
  scan2_k<<<1, 128, 0, stream>>>(bsum, nb);
  scan3_k<<<nb, 256, 0, stream>>>(offs, bsum);
  scatter_k<<<eb, 256, 0, stream>>>(ei, offs, cursor, ssrc);

  int nx4 = N_NODES * 256 / 4;
  conv_bf16_k<<<(nx4 + 255) / 256, 256, 0, stream>>>((const float4*)x, (uint2*)xbf, nx4);
  packW1_k<<<(256 * 320 + 255) / 256, 256, 0, stream>>>(W1, Wp1);
  packW23_k<<<(64 * 320 + 255) / 256, 256, 0, stream>>>(W2, W3, Wp23);

  dim3 gg(5, 313);   // panel-fast: 5 panels of one A row-tile are consecutive
  int aggb = N_NODES / 2;   // 10000 blocks, 2 nodes each

  // ---- layer 1 ----
  mfma_gemm_k<8, 64><<<gg, 256, 0, stream>>>(xbf, Wp1, xwb,
                                             att_src1, att_dst1, nullptr, nullptr,
                                             a_s, a_d, N_NODES);
  agg1_k<<<aggb, 640, 0, stream>>>(offs, ssrc, a_s, a_d, (const uint2*)xwb, b1, h1b);

  // ---- layers 2+3 fused ----
  mfma_gemm_k<2, 32><<<gg, 256, 0, stream>>>(h1b, Wp23, xwb,
                                             att_src2, att_dst2, att_src3, att_dst3,
                                             a_s, a_d, N_NODES);
  agg23_k<<<aggb, 640, 0, stream>>>(offs, ssrc, a_s, a_d, (const uint2*)xwb, b2, b3,
                                    out, out + (size_t)N_NODES * 32,
                                    out + (size_t)2 * N_NODES * 32);
}

// Round 18
// 200.038 us; speedup vs baseline: 1.1523x; 1.1523x over previous
//
#include <hip/hip_runtime.h>
#include <math.h>

#define N_NODES 20000
#define N_EDGES 320000
#define EP (N_EDGES + N_NODES)   // with self loops
#define HEADS 5

typedef __attribute__((ext_vector_type(8))) __bf16 bf16x8;
typedef __attribute__((ext_vector_type(4))) float f32x4;

__device__ __forceinline__ float lrelu(float s) { return (s > 0.f) ? s : 0.2f * s; }

// fp32 -> bf16 bits, round-to-nearest-even
__device__ __forceinline__ unsigned f2bf(float f) {
  unsigned u = __float_as_uint(f);
  return (u + 0x7fffu + ((u >> 16) & 1u)) >> 16;
}

// ---------------- CSR build ----------------
__global__ void count_deg_k(const int* __restrict__ ei, int* __restrict__ deg) {
  int e = blockIdx.x * blockDim.x + threadIdx.x;
  if (e >= EP) return;
  int dst = (e < N_EDGES) ? ei[N_EDGES + e] : (e - N_EDGES);
  atomicAdd(&deg[dst], 1);
}

__global__ __launch_bounds__(256) void scan1_k(const int* __restrict__ deg,
                                               int* __restrict__ offs,
                                               int* __restrict__ bsum) {
  __shared__ int buf[256];
  int tid = threadIdx.x, i = blockIdx.x * 256 + tid;
  int v = (i < N_NODES) ? deg[i] : 0;
  buf[tid] = v;
  __syncthreads();
  for (int o = 1; o < 256; o <<= 1) {
    int t = (tid >= o) ? buf[tid - o] : 0;
    __syncthreads();
    buf[tid] += t;
    __syncthreads();
  }
  if (i < N_NODES) offs[i] = buf[tid] - v;   // block-local exclusive
  if (tid == 255) bsum[blockIdx.x] = buf[255];
}

__global__ __launch_bounds__(128) void scan2_k(int* __restrict__ bsum, int nb) {
  __shared__ int buf[128];
  int tid = threadIdx.x;
  int v = (tid < nb) ? bsum[tid] : 0;
  buf[tid] = v;
  __syncthreads();
  for (int o = 1; o < 128; o <<= 1) {
    int t = (tid >= o) ? buf[tid - o] : 0;
    __syncthreads();
    buf[tid] += t;
    __syncthreads();
  }
  if (tid < nb) bsum[tid] = buf[tid] - v;    // exclusive
}

__global__ void scan3_k(int* __restrict__ offs, const int* __restrict__ bsum) {
  int i = blockIdx.x * 256 + threadIdx.x;
  if (i < N_NODES) offs[i] += bsum[blockIdx.x];
  if (i == 0) offs[N_NODES] = EP;
}

__global__ void scatter_k(const int* __restrict__ ei, const int* __restrict__ offs,
                          int* __restrict__ cursor, int* __restrict__ ssrc) {
  int e = blockIdx.x * blockDim.x + threadIdx.x;
  if (e >= EP) return;
  int src, dst;
  if (e < N_EDGES) { src = ei[e]; dst = ei[N_EDGES + e]; }
  else             { src = e - N_EDGES; dst = src; }
  int pos = atomicAdd(&cursor[dst], 1);
  ssrc[offs[dst] + pos] = src;
}

// ---------------- fp32 -> bf16 convert (elementwise, float4 -> uint2) ----------------
__global__ __launch_bounds__(256) void conv_bf16_k(const float4* __restrict__ src,
                                                   uint2* __restrict__ dst, int n4) {
  int t = blockIdx.x * blockDim.x + threadIdx.x;
  if (t >= n4) return;
  float4 v = src[t];
  unsigned p0 = f2bf(v.x) | (f2bf(v.y) << 16);
  unsigned p1 = f2bf(v.z) | (f2bf(v.w) << 16);
  dst[t] = make_uint2(p0, p1);
}

// ---------------- pack W1[256][320] -> MFMA B-fragment order, bf16 ----------------
__global__ void packW1_k(const float* __restrict__ W, unsigned short* __restrict__ Wp) {
  int t = blockIdx.x * blockDim.x + threadIdx.x;
  if (t >= 256 * 320) return;
  int k = t / 320, n = t % 320;
  int gnt = n >> 4, ll = n & 15;
  int ks = k >> 5, kr = k & 31;
  int lh = kr >> 3, i = kr & 7;
  Wp[(((size_t)gnt * 8 + ks) * 64 + lh * 16 + ll) * 8 + i] = (unsigned short)f2bf(W[t]);
}

// ---------------- pack [W2|W3] (64x320 combined) -> fragment order, bf16 ----------------
__global__ void packW23_k(const float* __restrict__ W2, const float* __restrict__ W3,
                          unsigned short* __restrict__ Wp) {
  int t = blockIdx.x * blockDim.x + threadIdx.x;
  if (t >= 64 * 320) return;
  int k = t / 320, n = t % 320;
  int u = n / 32, c = n % 32;
  float val = (u < HEADS) ? W2[k * 160 + u * 32 + c] : W3[k * 160 + (u - HEADS) * 32 + c];
  int gnt = n >> 4, ll = n & 15;
  int ks = k >> 5, kr = k & 31;
  int lh = kr >> 3, i = kr & 7;
  Wp[(((size_t)gnt * 2 + ks) * 64 + lh * 16 + ll) * 8 + i] = (unsigned short)f2bf(val);
}

// ---------------- MFMA GEMM (bf16 in, fp32 acc) + fused att-sums ----------------
// Grid (5, 313) panel-fast. Block = 64 rows x 64 cols, 4 waves, no LDS/barriers.
template <int KSTEPS, int CH>
__global__ __launch_bounds__(256) void mfma_gemm_k(
    const unsigned short* __restrict__ A, const unsigned short* __restrict__ Bp,
    unsigned short* __restrict__ Cb,
    const float* __restrict__ attAs, const float* __restrict__ attAd,
    const float* __restrict__ attBs, const float* __restrict__ attBd,
    float* __restrict__ as_out, float* __restrict__ ad_out, int M) {
  constexpr int K = KSTEPS * 32;
  int panel = blockIdx.x;
  int bm = blockIdx.y * 64;
  int w = threadIdx.x >> 6;
  int l = threadIdx.x & 63;
  int ll = l & 15, lh = l >> 4;

  int arow = bm + w * 16 + ll;
  if (arow >= M) arow = M - 1;          // clamp; writes are guarded
  const unsigned short* ap = A + (size_t)arow * K + lh * 8;

  f32x4 acc[4] = {};
  for (int ks = 0; ks < KSTEPS; ks++) {
    bf16x8 af = *(const bf16x8*)(ap + ks * 32);
#pragma unroll
    for (int nt = 0; nt < 4; nt++) {
      bf16x8 bf = *(const bf16x8*)(Bp + (((size_t)(panel * 4 + nt) * KSTEPS + ks) * 64 + l) * 8);
      acc[nt] = __builtin_amdgcn_mfma_f32_16x16x32_bf16(af, bf, acc[nt], 0, 0, 0);
    }
  }

  int row0 = bm + w * 16 + lh * 4;
#pragma unroll
  for (int j = 0; j < 4; j++) {
    int r = row0 + j;
    if (r < M) {
#pragma unroll
      for (int nt = 0; nt < 4; nt++)
        Cb[((size_t)panel * M + r) * 64 + nt * 16 + ll] = (unsigned short)f2bf(acc[nt][j]);
    }
  }

  float ws[4], wd[4];
  if (CH == 64) {
#pragma unroll
    for (int nt = 0; nt < 4; nt++) {
      ws[nt] = attAs[panel * 64 + nt * 16 + ll];
      wd[nt] = attAd[panel * 64 + nt * 16 + ll];
    }
  } else {
#pragma unroll
    for (int nt = 0; nt < 4; nt++) {
      int u = panel * 2 + (nt >> 1);
      int c = (nt & 1) * 16 + ll;
      const float* s = (u < HEADS) ? attAs + u * 32 : attBs + (u - HEADS) * 32;
      const float* d = (u < HEADS) ? attAd + u * 32 : attBd + (u - HEADS) * 32;
      ws[nt] = s[c]; wd[nt] = d[c];
    }
  }
#pragma unroll
  for (int j = 0; j < 4; j++) {
    int r = row0 + j;
    if (CH == 64) {
      float ps = acc[0][j] * ws[0] + acc[1][j] * ws[1] + acc[2][j] * ws[2] + acc[3][j] * ws[3];
      float pd = acc[0][j] * wd[0] + acc[1][j] * wd[1] + acc[2][j] * wd[2] + acc[3][j] * wd[3];
#pragma unroll
      for (int o = 1; o < 16; o <<= 1) {
        ps += __shfl_xor(ps, o);
        pd += __shfl_xor(pd, o);
      }
      if (ll == 0 && r < M) {
        as_out[(size_t)panel * M + r] = ps;
        ad_out[(size_t)panel * M + r] = pd;
      }
    } else {
      float ls = acc[0][j] * ws[0] + acc[1][j] * ws[1];
      float ld = acc[0][j] * wd[0] + acc[1][j] * wd[1];
      float hs = acc[2][j] * ws[2] + acc[3][j] * ws[3];
      float hd = acc[2][j] * wd[2] + acc[3][j] * wd[3];
#pragma unroll
      for (int o = 1; o < 16; o <<= 1) {
        ls += __shfl_xor(ls, o); ld += __shfl_xor(ld, o);
        hs += __shfl_xor(hs, o); hd += __shfl_xor(hd, o);
      }
      if (ll == 0 && r < M) {
        int ulo = panel * 2, uhi = panel * 2 + 1;
        as_out[(size_t)ulo * M + r] = ls;  ad_out[(size_t)ulo * M + r] = ld;
        as_out[(size_t)uhi * M + r] = hs;  ad_out[(size_t)uhi * M + r] = hd;
      }
    }
  }
}

// bf16-quad load helper: uint2 -> 4 floats
__device__ __forceinline__ void bf4(uint2 v, float& f0, float& f1, float& f2, float& f3) {
  f0 = __uint_as_float(v.x << 16);
  f1 = __uint_as_float(v.x & 0xffff0000u);
  f2 = __uint_as_float(v.y << 16);
  f3 = __uint_as_float(v.y & 0xffff0000u);
}

// ---------------- layer 1: block per node, 5 waves (wave = head), LDS reduce ----------------
// R18: LDS alpha staging — after the in-register softmax each wave writes its
// 64 {alpha, src} entries to private LDS (same-wave dep, no barrier; alpha
// pre-zeroed for tail lanes). The gather reads ONE ds_read per 4-edge group
// (broadcast within 16-lane groups) instead of 3 ds_bpermute + clamp-selects.
// Wave-uniform guards skip whole groups past deg.
__global__ __launch_bounds__(320) void agg1_k(const int* __restrict__ offs,
                                              const int* __restrict__ ssrc,
                                              const float* __restrict__ a_s,
                                              const float* __restrict__ a_d,
                                              const uint2* __restrict__ xwb,
                                              const float* __restrict__ b1,
                                              unsigned short* __restrict__ h1b) {
  int n = blockIdx.x;
  int u = threadIdx.x >> 6;
  int lane = threadIdx.x & 63;
  int off = offs[n], end = offs[n + 1];
  int deg = end - off;
  float ad = a_d[(size_t)u * N_NODES + n];
  const float* asl = a_s + (size_t)u * N_NODES;
  const uint2* xb  = xwb + (size_t)u * N_NODES * 16;
  int g = lane >> 4, q = lane & 15;
  float ax = 0.f, ay = 0.f, az = 0.f, aw = 0.f;

  __shared__ uint2 eLds[HEADS][64];
  __shared__ float sacc[HEADS][64];

  if (deg <= 64) {
    int s = 0;
    float e = -1e30f;
    if (lane < deg) { s = ssrc[off + lane]; e = lrelu(asl[s] + ad); }
    float m = e;
#pragma unroll
    for (int o = 32; o > 0; o >>= 1) m = fmaxf(m, __shfl_xor(m, o));
    float p = (lane < deg) ? __expf(e - m) : 0.f;
    float den = p;
#pragma unroll
    for (int o = 32; o > 0; o >>= 1) den += __shfl_xor(den, o);
    float alpha = p * (1.f / (den + 1e-16f));   // 0 for lane >= deg

    eLds[u][lane] = make_uint2(__float_as_uint(alpha), (unsigned)s);  // s=0 for tail

    for (int base = 0; base < deg; base += 16) {
      float alv[4];
      uint2 v[4];
#pragma unroll
      for (int t = 0; t < 4; t++) {
        int b4 = base + t * 4;
        if (b4 < deg) {                        // wave-uniform guard
          uint2 es = eLds[u][b4 + g];          // broadcast within group
          alv[t] = __uint_as_float(es.x);      // 0 for clamped edges
          v[t] = xb[(size_t)es.y * 16 + q];
        }
      }
#pragma unroll
      for (int t = 0; t < 4; t++) {
        if (base + t * 4 < deg) {
          float f0, f1, f2, f3;
          bf4(v[t], f0, f1, f2, f3);
          ax += alv[t] * f0; ay += alv[t] * f1;
          az += alv[t] * f2; aw += alv[t] * f3;
        }
      }
    }
  } else {
    float m = -1e30f;
    for (int i = off + lane; i < end; i += 64) m = fmaxf(m, lrelu(asl[ssrc[i]] + ad));
#pragma unroll
    for (int o = 32; o > 0; o >>= 1) m = fmaxf(m, __shfl_xor(m, o));
    float den = 0.f;
    for (int i = off + lane; i < end; i += 64) den += __expf(lrelu(asl[ssrc[i]] + ad) - m);
#pragma unroll
    for (int o = 32; o > 0; o >>= 1) den += __shfl_xor(den, o);
    float inv = 1.f / (den + 1e-16f);
    for (int base = off; base < end; base += 4) {
      int e = base + g;
      if (e < end) {
        int sv = ssrc[e];
        float al = __expf(lrelu(asl[sv] + ad) - m) * inv;
        float f0, f1, f2, f3;
        bf4(xb[(size_t)sv * 16 + q], f0, f1, f2, f3);
        ax += al * f0; ay += al * f1; az += al * f2; aw += al * f3;
      }
    }
  }

#pragma unroll
  for (int o = 16; o < 64; o <<= 1) {
    ax += __shfl_xor(ax, o); ay += __shfl_xor(ay, o);
    az += __shfl_xor(az, o); aw += __shfl_xor(aw, o);
  }

  if (g == 0) *(float4*)&sacc[u][q * 4] = make_float4(ax, ay, az, aw);
  __syncthreads();
  if (threadIdx.x < 64) {
    int t = threadIdx.x;
    float v = sacc[0][t] + sacc[1][t] + sacc[2][t] + sacc[3][t] + sacc[4][t];
    v = fmaxf(v * 0.2f + b1[t], 0.f);
    h1b[(size_t)n * 64 + t] = (unsigned short)f2bf(v);
  }
}

// ---------------- layers 2+3: block per node, 5 waves (wave = pair 2g,2g+1) ----------------
// LDS entry = {alpha_lo, alpha_hi, src, pad}; one ds_read_b128 per 4-edge group.
__global__ __launch_bounds__(320) void agg23_k(const int* __restrict__ offs,
                                               const int* __restrict__ ssrc,
                                               const float* __restrict__ a_s,
                                               const float* __restrict__ a_d,
                                               const uint2* __restrict__ xwb,
                                               const float* __restrict__ b2,
                                               const float* __restrict__ b3,
                                               float* __restrict__ z_out,
                                               float* __restrict__ mu_out,
                                               float* __restrict__ lv_out) {
  int n = blockIdx.x;
  int gp = threadIdx.x >> 6;
  int lane = threadIdx.x & 63;
  int ulo = 2 * gp, uhi = 2 * gp + 1;
  int off = offs[n], end = offs[n + 1];
  int deg = end - off;
  float adlo = a_d[(size_t)ulo * N_NODES + n];
  float adhi = a_d[(size_t)uhi * N_NODES + n];
  const float* aslo = a_s + (size_t)ulo * N_NODES;
  const float* ashi = a_s + (size_t)uhi * N_NODES;
  const uint2* xb   = xwb + (size_t)gp * N_NODES * 16;
  int g = lane >> 4, q = lane & 15;
  float ax = 0.f, ay = 0.f, az = 0.f, aw = 0.f;

  __shared__ uint4 eLds[HEADS][64];
  __shared__ float sacc[HEADS][2][32];

  if (deg <= 64) {
    int s = 0;
    float elo = -1e30f, ehi = -1e30f;
    if (lane < deg) {
      s = ssrc[off + lane];
      elo = lrelu(aslo[s] + adlo);
      ehi = lrelu(ashi[s] + adhi);
    }
    float mlo = elo, mhi = ehi;
#pragma unroll
    for (int o = 32; o > 0; o >>= 1) {
      mlo = fmaxf(mlo, __shfl_xor(mlo, o));
      mhi = fmaxf(mhi, __shfl_xor(mhi, o));
    }
    float plo = (lane < deg) ? __expf(elo - mlo) : 0.f;
    float phi = (lane < deg) ? __expf(ehi - mhi) : 0.f;
    float dlo = plo, dhi = phi;
#pragma unroll
    for (int o = 32; o > 0; o >>= 1) {
      dlo += __shfl_xor(dlo, o);
      dhi += __shfl_xor(dhi, o);
    }
    float allo = plo * (1.f / (dlo + 1e-16f));   // 0 for tail lanes
    float alhi = phi * (1.f / (dhi + 1e-16f));

    eLds[gp][lane] = make_uint4(__float_as_uint(allo), __float_as_uint(alhi),
                                (unsigned)s, 0u);

    for (int base = 0; base < deg; base += 16) {
      float alv[4];
      uint2 v[4];
#pragma unroll
      for (int t = 0; t < 4; t++) {
        int b4 = base + t * 4;
        if (b4 < deg) {                        // wave-uniform guard
          uint4 es = eLds[gp][b4 + g];         // broadcast within group
          alv[t] = __uint_as_float((q < 8) ? es.x : es.y);
          v[t] = xb[(size_t)es.z * 16 + q];
        }
      }
#pragma unroll
      for (int t = 0; t < 4; t++) {
        if (base + t * 4 < deg) {
          float f0, f1, f2, f3;
          bf4(v[t], f0, f1, f2, f3);
          ax += alv[t] * f0; ay += alv[t] * f1;
          az += alv[t] * f2; aw += alv[t] * f3;
        }
      }
    }
  } else {
    float mlo = -1e30f, mhi = -1e30f;
    for (int i = off + lane; i < end; i += 64) {
      int sv = ssrc[i];
      mlo = fmaxf(mlo, lrelu(aslo[sv] + adlo));
      mhi = fmaxf(mhi, lrelu(ashi[sv] + adhi));
    }
#pragma unroll
    for (int o = 32; o > 0; o >>= 1) {
      mlo = fmaxf(mlo, __shfl_xor(mlo, o));
      mhi = fmaxf(mhi, __shfl_xor(mhi, o));
    }
    float dlo = 0.f, dhi = 0.f;
    for (int i = off + lane; i < end; i += 64) {
      int sv = ssrc[i];
      dlo += __expf(lrelu(aslo[sv] + adlo) - mlo);
      dhi += __expf(lrelu(ashi[sv] + adhi) - mhi);
    }
#pragma unroll
    for (int o = 32; o > 0; o >>= 1) {
      dlo += __shfl_xor(dlo, o);
      dhi += __shfl_xor(dhi, o);
    }
    float ilo = 1.f / (dlo + 1e-16f), ihi = 1.f / (dhi + 1e-16f);
    for (int base = off; base < end; base += 4) {
      int e = base + g;
      if (e < end) {
        int sv = ssrc[e];
        float al;
        if (q < 8) al = __expf(lrelu(aslo[sv] + adlo) - mlo) * ilo;
        else       al = __expf(lrelu(ashi[sv] + adhi) - mhi) * ihi;
        float f0, f1, f2, f3;
        bf4(xb[(size_t)sv * 16 + q], f0, f1, f2, f3);
        ax += al * f0; ay += al * f1; az += al * f2; aw += al * f3;
      }
    }
  }

#pragma unroll
  for (int o = 16; o < 64; o <<= 1) {
    ax += __shfl_xor(ax, o); ay += __shfl_xor(ay, o);
    az += __shfl_xor(az, o); aw += __shfl_xor(aw, o);
  }

  if (g == 0)
    *(float4*)&sacc[gp][q >> 3][(q & 7) * 4] = make_float4(ax, ay, az, aw);
  __syncthreads();
  if (threadIdx.x < 64) {
    int t = threadIdx.x;
    if (t < 32) {
      float v = sacc[0][0][t] + sacc[0][1][t] + sacc[1][0][t] + sacc[1][1][t] + sacc[2][0][t];
      v = v * 0.2f + b2[t];
      z_out[(size_t)n * 32 + t]  = v;
      mu_out[(size_t)n * 32 + t] = v;
    } else {
      int c = t - 32;
      float v = sacc[2][1][c] + sacc[3][0][c] + sacc[3][1][c] + sacc[4][0][c] + sacc[4][1][c];
      v = v * 0.2f + b3[c];
      lv_out[(size_t)n * 32 + c] = v;
    }
  }
}

// ---------------- launch ----------------
extern "C" void kernel_launch(void* const* d_in, const int* in_sizes, int n_in,
                              void* d_out, int out_size, void* d_ws, size_t ws_size,
                              hipStream_t stream) {
  const float* x        = (const float*)d_in[0];
  const int*   ei       = (const int*)d_in[1];
  const float* W1       = (const float*)d_in[2];
  const float* att_src1 = (const float*)d_in[3];
  const float* att_dst1 = (const float*)d_in[4];
  const float* b1       = (const float*)d_in[5];
  const float* W2       = (const float*)d_in[6];
  const float* att_src2 = (const float*)d_in[7];
  const float* att_dst2 = (const float*)d_in[8];
  const float* b2       = (const float*)d_in[9];
  const float* W3       = (const float*)d_in[10];
  const float* att_src3 = (const float*)d_in[11];
  const float* att_dst3 = (const float*)d_in[12];
  const float* b3       = (const float*)d_in[13];
  float* out = (float*)d_out;

  char* w = (char*)d_ws;
  auto alloc = [&](size_t bytes) -> void* {
    void* p = (void*)w;
    w += (bytes + 255) & ~(size_t)255;
    return p;
  };
  int*            deg    = (int*)alloc((size_t)N_NODES * 4);
  int*            offs   = (int*)alloc((size_t)(N_NODES + 1) * 4);
  int*            cursor = (int*)alloc((size_t)N_NODES * 4);
  int*            bsum   = (int*)alloc((size_t)128 * 4);
  int*            ssrc   = (int*)alloc((size_t)EP * 4);
  unsigned short* xwb    = (unsigned short*)alloc((size_t)N_NODES * 320 * 2);  // 12.8 MB
  float*          a_s    = (float*)alloc((size_t)N_NODES * 10 * 4);
  float*          a_d    = (float*)alloc((size_t)N_NODES * 10 * 4);
  unsigned short* h1b    = (unsigned short*)alloc((size_t)N_NODES * 64 * 2);   // 2.56 MB
  unsigned short* xbf    = (unsigned short*)alloc((size_t)N_NODES * 256 * 2);  // 10.24 MB
  unsigned short* Wp1    = (unsigned short*)alloc((size_t)256 * 320 * 2);
  unsigned short* Wp23   = (unsigned short*)alloc((size_t)64 * 320 * 2);
  // total ~29 MB (< proven ~34 MB)

  hipMemsetAsync(deg, 0, (size_t)N_NODES * 4, stream);
  hipMemsetAsync(cursor, 0, (size_t)N_NODES * 4, stream);

  int eb = (EP + 255) / 256;
  int nb = (N_NODES + 255) / 256;   // 79
  count_deg_k<<<eb, 256, 0, stream>>>(ei, deg);
  scan1_k<<<nb, 256, 0, stream>>>(deg, offs, bsum);
  scan2_k<<<1, 128, 0, stream>>>(bsum, nb);
  scan3_k<<<nb, 256, 0, stream>>>(offs, bsum);
  scatter_k<<<eb, 256, 0, stream>>>(ei, offs, cursor, ssrc);

  int nx4 = N_NODES * 256 / 4;
  conv_bf16_k<<<(nx4 + 255) / 256, 256, 0, stream>>>((const float4*)x, (uint2*)xbf, nx4);
  packW1_k<<<(256 * 320 + 255) / 256, 256, 0, stream>>>(W1, Wp1);
  packW23_k<<<(64 * 320 + 255) / 256, 256, 0, stream>>>(W2, W3, Wp23);

  dim3 gg(5, 313);   // panel-fast: 5 panels of one A row-tile are consecutive

  // ---- layer 1 ----
  mfma_gemm_k<8, 64><<<gg, 256, 0, stream>>>(xbf, Wp1, xwb,
                                             att_src1, att_dst1, nullptr, nullptr,
                                             a_s, a_d, N_NODES);
  agg1_k<<<N_NODES, 320, 0, stream>>>(offs, ssrc, a_s, a_d, (const uint2*)xwb, b1, h1b);

  // ---- layers 2+3 fused ----
  mfma_gemm_k<2, 32><<<gg, 256, 0, stream>>>(h1b, Wp23, xwb,
                                             att_src2, att_dst2, att_src3, att_dst3,
                                             a_s, a_d, N_NODES);
  agg23_k<<<N_NODES, 320, 0, stream>>>(offs, ssrc, a_s, a_d, (const uint2*)xwb, b2, b3,
                                       out, out + (size_t)N_NODES * 32,
                                       out + (size_t)2 * N_NODES * 32);
}

// Round 19
// 195.755 us; speedup vs baseline: 1.1775x; 1.0219x over previous
//
#include <hip/hip_runtime.h>
#include <math.h>

#define N_NODES 20000
#define N_EDGES 320000
#define EP (N_EDGES + N_NODES)   // with self loops
#define HEADS 5

typedef __attribute__((ext_vector_type(8))) __bf16 bf16x8;
typedef __attribute__((ext_vector_type(4))) float f32x4;

__device__ __forceinline__ float lrelu(float s) { return (s > 0.f) ? s : 0.2f * s; }

// fp32 -> bf16 bits, round-to-nearest-even
__device__ __forceinline__ unsigned f2bf(float f) {
  unsigned u = __float_as_uint(f);
  return (u + 0x7fffu + ((u >> 16) & 1u)) >> 16;
}

// ---------------- CSR build ----------------
__global__ void count_deg_k(const int* __restrict__ ei, int* __restrict__ deg) {
  int e = blockIdx.x * blockDim.x + threadIdx.x;
  if (e >= EP) return;
  int dst = (e < N_EDGES) ? ei[N_EDGES + e] : (e - N_EDGES);
  atomicAdd(&deg[dst], 1);
}

__global__ __launch_bounds__(256) void scan1_k(const int* __restrict__ deg,
                                               int* __restrict__ offs,
                                               int* __restrict__ bsum) {
  __shared__ int buf[256];
  int tid = threadIdx.x, i = blockIdx.x * 256 + tid;
  int v = (i < N_NODES) ? deg[i] : 0;
  buf[tid] = v;
  __syncthreads();
  for (int o = 1; o < 256; o <<= 1) {
    int t = (tid >= o) ? buf[tid - o] : 0;
    __syncthreads();
    buf[tid] += t;
    __syncthreads();
  }
  if (i < N_NODES) offs[i] = buf[tid] - v;   // block-local exclusive
  if (tid == 255) bsum[blockIdx.x] = buf[255];
}

__global__ __launch_bounds__(128) void scan2_k(int* __restrict__ bsum, int nb) {
  __shared__ int buf[128];
  int tid = threadIdx.x;
  int v = (tid < nb) ? bsum[tid] : 0;
  buf[tid] = v;
  __syncthreads();
  for (int o = 1; o < 128; o <<= 1) {
    int t = (tid >= o) ? buf[tid - o] : 0;
    __syncthreads();
    buf[tid] += t;
    __syncthreads();
  }
  if (tid < nb) bsum[tid] = buf[tid] - v;    // exclusive
}

__global__ void scan3_k(int* __restrict__ offs, const int* __restrict__ bsum) {
  int i = blockIdx.x * 256 + threadIdx.x;
  if (i < N_NODES) offs[i] += bsum[blockIdx.x];
  if (i == 0) offs[N_NODES] = EP;
}

__global__ void scatter_k(const int* __restrict__ ei, const int* __restrict__ offs,
                          int* __restrict__ cursor, int* __restrict__ ssrc) {
  int e = blockIdx.x * blockDim.x + threadIdx.x;
  if (e >= EP) return;
  int src, dst;
  if (e < N_EDGES) { src = ei[e]; dst = ei[N_EDGES + e]; }
  else             { src = e - N_EDGES; dst = src; }
  int pos = atomicAdd(&cursor[dst], 1);
  ssrc[offs[dst] + pos] = src;
}

// ---------------- fp32 -> bf16 convert (elementwise, float4 -> uint2) ----------------
__global__ __launch_bounds__(256) void conv_bf16_k(const float4* __restrict__ src,
                                                   uint2* __restrict__ dst, int n4) {
  int t = blockIdx.x * blockDim.x + threadIdx.x;
  if (t >= n4) return;
  float4 v = src[t];
  unsigned p0 = f2bf(v.x) | (f2bf(v.y) << 16);
  unsigned p1 = f2bf(v.z) | (f2bf(v.w) << 16);
  dst[t] = make_uint2(p0, p1);
}

// ---------------- pack W1[256][320] -> MFMA B-fragment order, bf16 ----------------
__global__ void packW1_k(const float* __restrict__ W, unsigned short* __restrict__ Wp) {
  int t = blockIdx.x * blockDim.x + threadIdx.x;
  if (t >= 256 * 320) return;
  int k = t / 320, n = t % 320;
  int gnt = n >> 4, ll = n & 15;
  int ks = k >> 5, kr = k & 31;
  int lh = kr >> 3, i = kr & 7;
  Wp[(((size_t)gnt * 8 + ks) * 64 + lh * 16 + ll) * 8 + i] = (unsigned short)f2bf(W[t]);
}

// ---------------- pack [W2|W3] (64x320 combined) -> fragment order, bf16 ----------------
__global__ void packW23_k(const float* __restrict__ W2, const float* __restrict__ W3,
                          unsigned short* __restrict__ Wp) {
  int t = blockIdx.x * blockDim.x + threadIdx.x;
  if (t >= 64 * 320) return;
  int k = t / 320, n = t % 320;
  int u = n / 32, c = n % 32;
  float val = (u < HEADS) ? W2[k * 160 + u * 32 + c] : W3[k * 160 + (u - HEADS) * 32 + c];
  int gnt = n >> 4, ll = n & 15;
  int ks = k >> 5, kr = k & 31;
  int lh = kr >> 3, i = kr & 7;
  Wp[(((size_t)gnt * 2 + ks) * 64 + lh * 16 + ll) * 8 + i] = (unsigned short)f2bf(val);
}

// ---------------- MFMA GEMM (bf16 in, fp32 acc) + fused att-sums ----------------
// Grid (5, 313) panel-fast. Block = 64 rows x 64 cols, 4 waves, no LDS/barriers.
template <int KSTEPS, int CH>
__global__ __launch_bounds__(256) void mfma_gemm_k(
    const unsigned short* __restrict__ A, const unsigned short* __restrict__ Bp,
    unsigned short* __restrict__ Cb,
    const float* __restrict__ attAs, const float* __restrict__ attAd,
    const float* __restrict__ attBs, const float* __restrict__ attBd,
    float* __restrict__ as_out, float* __restrict__ ad_out, int M) {
  constexpr int K = KSTEPS * 32;
  int panel = blockIdx.x;
  int bm = blockIdx.y * 64;
  int w = threadIdx.x >> 6;
  int l = threadIdx.x & 63;
  int ll = l & 15, lh = l >> 4;

  int arow = bm + w * 16 + ll;
  if (arow >= M) arow = M - 1;          // clamp; writes are guarded
  const unsigned short* ap = A + (size_t)arow * K + lh * 8;

  f32x4 acc[4] = {};
  for (int ks = 0; ks < KSTEPS; ks++) {
    bf16x8 af = *(const bf16x8*)(ap + ks * 32);
#pragma unroll
    for (int nt = 0; nt < 4; nt++) {
      bf16x8 bf = *(const bf16x8*)(Bp + (((size_t)(panel * 4 + nt) * KSTEPS + ks) * 64 + l) * 8);
      acc[nt] = __builtin_amdgcn_mfma_f32_16x16x32_bf16(af, bf, acc[nt], 0, 0, 0);
    }
  }

  int row0 = bm + w * 16 + lh * 4;
#pragma unroll
  for (int j = 0; j < 4; j++) {
    int r = row0 + j;
    if (r < M) {
#pragma unroll
      for (int nt = 0; nt < 4; nt++)
        Cb[((size_t)panel * M + r) * 64 + nt * 16 + ll] = (unsigned short)f2bf(acc[nt][j]);
    }
  }

  float ws[4], wd[4];
  if (CH == 64) {
#pragma unroll
    for (int nt = 0; nt < 4; nt++) {
      ws[nt] = attAs[panel * 64 + nt * 16 + ll];
      wd[nt] = attAd[panel * 64 + nt * 16 + ll];
    }
  } else {
#pragma unroll
    for (int nt = 0; nt < 4; nt++) {
      int u = panel * 2 + (nt >> 1);
      int c = (nt & 1) * 16 + ll;
      const float* s = (u < HEADS) ? attAs + u * 32 : attBs + (u - HEADS) * 32;
      const float* d = (u < HEADS) ? attAd + u * 32 : attBd + (u - HEADS) * 32;
      ws[nt] = s[c]; wd[nt] = d[c];
    }
  }
#pragma unroll
  for (int j = 0; j < 4; j++) {
    int r = row0 + j;
    if (CH == 64) {
      float ps = acc[0][j] * ws[0] + acc[1][j] * ws[1] + acc[2][j] * ws[2] + acc[3][j] * ws[3];
      float pd = acc[0][j] * wd[0] + acc[1][j] * wd[1] + acc[2][j] * wd[2] + acc[3][j] * wd[3];
#pragma unroll
      for (int o = 1; o < 16; o <<= 1) {
        ps += __shfl_xor(ps, o);
        pd += __shfl_xor(pd, o);
      }
      if (ll == 0 && r < M) {
        as_out[(size_t)panel * M + r] = ps;
        ad_out[(size_t)panel * M + r] = pd;
      }
    } else {
      float ls = acc[0][j] * ws[0] + acc[1][j] * ws[1];
      float ld = acc[0][j] * wd[0] + acc[1][j] * wd[1];
      float hs = acc[2][j] * ws[2] + acc[3][j] * ws[3];
      float hd = acc[2][j] * wd[2] + acc[3][j] * wd[3];
#pragma unroll
      for (int o = 1; o < 16; o <<= 1) {
        ls += __shfl_xor(ls, o); ld += __shfl_xor(ld, o);
        hs += __shfl_xor(hs, o); hd += __shfl_xor(hd, o);
      }
      if (ll == 0 && r < M) {
        int ulo = panel * 2, uhi = panel * 2 + 1;
        as_out[(size_t)ulo * M + r] = ls;  ad_out[(size_t)ulo * M + r] = ld;
        as_out[(size_t)uhi * M + r] = hs;  ad_out[(size_t)uhi * M + r] = hd;
      }
    }
  }
}

// bf16-quad load helper: uint2 -> 4 floats
__device__ __forceinline__ void bf4(uint2 v, float& f0, float& f1, float& f2, float& f3) {
  f0 = __uint_as_float(v.x << 16);
  f1 = __uint_as_float(v.x & 0xffff0000u);
  f2 = __uint_as_float(v.y << 16);
  f3 = __uint_as_float(v.y & 0xffff0000u);
}

// ---------------- layer 1 aggregate: ONE WAVE per (unit, node), UNIT-MAJOR ----------------
// R19: unit-major dispatch -> all XCDs gather from the SAME 2.56 MB bf16 slice
// per temporal phase (fits 4 MB per-XCD L2; node-major's 12.8 MB did not ->
// 91 MB L3 streaming). Partials to part[u][n][64] fp32 (coalesced, no atomics,
// no block reduce, no barrier). LDS alpha staging + wave-uniform guards (R18).
__global__ __launch_bounds__(256) void agg1u_k(const int* __restrict__ offs,
                                               const int* __restrict__ ssrc,
                                               const float* __restrict__ a_s,
                                               const float* __restrict__ a_d,
                                               const uint2* __restrict__ xwb,
                                               float* __restrict__ part) {
  int wid = blockIdx.x * 4 + (threadIdx.x >> 6);
  int lane = threadIdx.x & 63;
  if (wid >= N_NODES * HEADS) return;
  int u = wid / N_NODES, n = wid - u * N_NODES;
  int w4 = threadIdx.x >> 6;
  int off = offs[n], end = offs[n + 1];
  int deg = end - off;
  float ad = a_d[(size_t)u * N_NODES + n];
  const float* asl = a_s + (size_t)u * N_NODES;
  const uint2* xb  = xwb + (size_t)u * N_NODES * 16;
  int g = lane >> 4, q = lane & 15;
  float ax = 0.f, ay = 0.f, az = 0.f, aw = 0.f;

  __shared__ uint2 eLds[4][64];

  if (deg <= 64) {
    int s = 0;
    float e = -1e30f;
    if (lane < deg) { s = ssrc[off + lane]; e = lrelu(asl[s] + ad); }
    float m = e;
#pragma unroll
    for (int o = 32; o > 0; o >>= 1) m = fmaxf(m, __shfl_xor(m, o));
    float p = (lane < deg) ? __expf(e - m) : 0.f;
    float den = p;
#pragma unroll
    for (int o = 32; o > 0; o >>= 1) den += __shfl_xor(den, o);
    float alpha = p * (1.f / (den + 1e-16f));   // 0 for tail lanes

    eLds[w4][lane] = make_uint2(__float_as_uint(alpha), (unsigned)s);

    for (int base = 0; base < deg; base += 16) {
      float alv[4];
      uint2 v[4];
#pragma unroll
      for (int t = 0; t < 4; t++) {
        int b4 = base + t * 4;
        if (b4 < deg) {                        // wave-uniform guard
          uint2 es = eLds[w4][b4 + g];         // broadcast within group
          alv[t] = __uint_as_float(es.x);
          v[t] = xb[(size_t)es.y * 16 + q];
        }
      }
#pragma unroll
      for (int t = 0; t < 4; t++) {
        if (base + t * 4 < deg) {
          float f0, f1, f2, f3;
          bf4(v[t], f0, f1, f2, f3);
          ax += alv[t] * f0; ay += alv[t] * f1;
          az += alv[t] * f2; aw += alv[t] * f3;
        }
      }
    }
  } else {
    float m = -1e30f;
    for (int i = off + lane; i < end; i += 64) m = fmaxf(m, lrelu(asl[ssrc[i]] + ad));
#pragma unroll
    for (int o = 32; o > 0; o >>= 1) m = fmaxf(m, __shfl_xor(m, o));
    float den = 0.f;
    for (int i = off + lane; i < end; i += 64) den += __expf(lrelu(asl[ssrc[i]] + ad) - m);
#pragma unroll
    for (int o = 32; o > 0; o >>= 1) den += __shfl_xor(den, o);
    float inv = 1.f / (den + 1e-16f);
    for (int base = off; base < end; base += 4) {
      int e = base + g;
      if (e < end) {
        int sv = ssrc[e];
        float al = __expf(lrelu(asl[sv] + ad) - m) * inv;
        float f0, f1, f2, f3;
        bf4(xb[(size_t)sv * 16 + q], f0, f1, f2, f3);
        ax += al * f0; ay += al * f1; az += al * f2; aw += al * f3;
      }
    }
  }

#pragma unroll
  for (int o = 16; o < 64; o <<= 1) {
    ax += __shfl_xor(ax, o); ay += __shfl_xor(ay, o);
    az += __shfl_xor(az, o); aw += __shfl_xor(aw, o);
  }
  if (g == 0)
    *(float4*)&part[((size_t)u * N_NODES + n) * 64 + q * 4] =
        make_float4(ax, ay, az, aw);
}

// ---------------- layer-1 reduce: mean over heads + bias + relu -> h1 bf16 ----------------
__global__ __launch_bounds__(256) void red1_k(const float* __restrict__ part,
                                              const float* __restrict__ b1,
                                              unsigned short* __restrict__ h1b) {
  int t = blockIdx.x * blockDim.x + threadIdx.x;   // n*16 + q
  if (t >= N_NODES * 16) return;
  int n = t >> 4, q = t & 15;
  float x = 0.f, y = 0.f, z = 0.f, w = 0.f;
#pragma unroll
  for (int h = 0; h < HEADS; h++) {
    float4 v = *(const float4*)&part[((size_t)h * N_NODES + n) * 64 + q * 4];
    x += v.x; y += v.y; z += v.z; w += v.w;
  }
  float4 bb = *(const float4*)&b1[q * 4];
  unsigned short r0 = (unsigned short)f2bf(fmaxf(x * 0.2f + bb.x, 0.f));
  unsigned short r1 = (unsigned short)f2bf(fmaxf(y * 0.2f + bb.y, 0.f));
  unsigned short r2 = (unsigned short)f2bf(fmaxf(z * 0.2f + bb.z, 0.f));
  unsigned short r3 = (unsigned short)f2bf(fmaxf(w * 0.2f + bb.w, 0.f));
  unsigned p0 = (unsigned)r0 | ((unsigned)r1 << 16);
  unsigned p1 = (unsigned)r2 | ((unsigned)r3 << 16);
  *(uint2*)&h1b[(size_t)n * 64 + q * 4] = make_uint2(p0, p1);
}

// ---------------- layers 2+3 aggregate: ONE WAVE per (pair, node), UNIT-MAJOR ----------------
// pair gp covers units (2gp, 2gp+1) in slice gp; partial -> part[gp][n][64]
// (cols 0-31 = unit lo, 32-63 = unit hi).
__global__ __launch_bounds__(256) void agg23u_k(const int* __restrict__ offs,
                                                const int* __restrict__ ssrc,
                                                const float* __restrict__ a_s,
                                                const float* __restrict__ a_d,
                                                const uint2* __restrict__ xwb,
                                                float* __restrict__ part) {
  int wid = blockIdx.x * 4 + (threadIdx.x >> 6);
  int lane = threadIdx.x & 63;
  if (wid >= N_NODES * HEADS) return;
  int gp = wid / N_NODES, n = wid - gp * N_NODES;
  int w4 = threadIdx.x >> 6;
  int ulo = 2 * gp, uhi = 2 * gp + 1;
  int off = offs[n], end = offs[n + 1];
  int deg = end - off;
  float adlo = a_d[(size_t)ulo * N_NODES + n];
  float adhi = a_d[(size_t)uhi * N_NODES + n];
  const float* aslo = a_s + (size_t)ulo * N_NODES;
  const float* ashi = a_s + (size_t)uhi * N_NODES;
  const uint2* xb   = xwb + (size_t)gp * N_NODES * 16;
  int g = lane >> 4, q = lane & 15;
  float ax = 0.f, ay = 0.f, az = 0.f, aw = 0.f;

  __shared__ uint4 eLds[4][64];

  if (deg <= 64) {
    int s = 0;
    float elo = -1e30f, ehi = -1e30f;
    if (lane < deg) {
      s = ssrc[off + lane];
      elo = lrelu(aslo[s] + adlo);
      ehi = lrelu(ashi[s] + adhi);
    }
    float mlo = elo, mhi = ehi;
#pragma unroll
    for (int o = 32; o > 0; o >>= 1) {
      mlo = fmaxf(mlo, __shfl_xor(mlo, o));
      mhi = fmaxf(mhi, __shfl_xor(mhi, o));
    }
    float plo = (lane < deg) ? __expf(elo - mlo) : 0.f;
    float phi = (lane < deg) ? __expf(ehi - mhi) : 0.f;
    float dlo = plo, dhi = phi;
#pragma unroll
    for (int o = 32; o > 0; o >>= 1) {
      dlo += __shfl_xor(dlo, o);
      dhi += __shfl_xor(dhi, o);
    }
    float allo = plo * (1.f / (dlo + 1e-16f));   // 0 for tail lanes
    float alhi = phi * (1.f / (dhi + 1e-16f));

    eLds[w4][lane] = make_uint4(__float_as_uint(allo), __float_as_uint(alhi),
                                (unsigned)s, 0u);

    for (int base = 0; base < deg; base += 16) {
      float alv[4];
      uint2 v[4];
#pragma unroll
      for (int t = 0; t < 4; t++) {
        int b4 = base + t * 4;
        if (b4 < deg) {                        // wave-uniform guard
          uint4 es = eLds[w4][b4 + g];         // broadcast within group
          alv[t] = __uint_as_float((q < 8) ? es.x : es.y);
          v[t] = xb[(size_t)es.z * 16 + q];
        }
      }
#pragma unroll
      for (int t = 0; t < 4; t++) {
        if (base + t * 4 < deg) {
          float f0, f1, f2, f3;
          bf4(v[t], f0, f1, f2, f3);
          ax += alv[t] * f0; ay += alv[t] * f1;
          az += alv[t] * f2; aw += alv[t] * f3;
        }
      }
    }
  } else {
    float mlo = -1e30f, mhi = -1e30f;
    for (int i = off + lane; i < end; i += 64) {
      int sv = ssrc[i];
      mlo = fmaxf(mlo, lrelu(aslo[sv] + adlo));
      mhi = fmaxf(mhi, lrelu(ashi[sv] + adhi));
    }
#pragma unroll
    for (int o = 32; o > 0; o >>= 1) {
      mlo = fmaxf(mlo, __shfl_xor(mlo, o));
      mhi = fmaxf(mhi, __shfl_xor(mhi, o));
    }
    float dlo = 0.f, dhi = 0.f;
    for (int i = off + lane; i < end; i += 64) {
      int sv = ssrc[i];
      dlo += __expf(lrelu(aslo[sv] + adlo) - mlo);
      dhi += __expf(lrelu(ashi[sv] + adhi) - mhi);
    }
#pragma unroll
    for (int o = 32; o > 0; o >>= 1) {
      dlo += __shfl_xor(dlo, o);
      dhi += __shfl_xor(dhi, o);
    }
    float ilo = 1.f / (dlo + 1e-16f), ihi = 1.f / (dhi + 1e-16f);
    for (int base = off; base < end; base += 4) {
      int e = base + g;
      if (e < end) {
        int sv = ssrc[e];
        float al;
        if (q < 8) al = __expf(lrelu(aslo[sv] + adlo) - mlo) * ilo;
        else       al = __expf(lrelu(ashi[sv] + adhi) - mhi) * ihi;
        float f0, f1, f2, f3;
        bf4(xb[(size_t)sv * 16 + q], f0, f1, f2, f3);
        ax += al * f0; ay += al * f1; az += al * f2; aw += al * f3;
      }
    }
  }

#pragma unroll
  for (int o = 16; o < 64; o <<= 1) {
    ax += __shfl_xor(ax, o); ay += __shfl_xor(ay, o);
    az += __shfl_xor(az, o); aw += __shfl_xor(aw, o);
  }
  if (g == 0)
    *(float4*)&part[((size_t)gp * N_NODES + n) * 64 + q * 4] =
        make_float4(ax, ay, az, aw);
}

// ---------------- layers 2+3 reduce: combine pairs -> z, mu, logvar ----------------
// layer2 units 0-4 = (gp0,lo),(gp0,hi),(gp1,lo),(gp1,hi),(gp2,lo);
// layer3 units 5-9 = (gp2,hi),(gp3,lo),(gp3,hi),(gp4,lo),(gp4,hi)
__global__ __launch_bounds__(256) void red23_k(const float* __restrict__ part,
                                               const float* __restrict__ b2,
                                               const float* __restrict__ b3,
                                               float* __restrict__ z_out,
                                               float* __restrict__ mu_out,
                                               float* __restrict__ lv_out) {
  int t = blockIdx.x * blockDim.x + threadIdx.x;   // n*8 + q
  if (t >= N_NODES * 8) return;
  int n = t >> 3, q = t & 7;
  int c = q * 4;
  auto P = [&](int g, int j) -> float4 {
    return *(const float4*)&part[((size_t)g * N_NODES + n) * 64 + j];
  };
  float4 a0 = P(0, c), a1 = P(0, 32 + c), a2 = P(1, c), a3 = P(1, 32 + c), a4 = P(2, c);
  float4 l0 = P(2, 32 + c), l1 = P(3, c), l2 = P(3, 32 + c), l3 = P(4, c), l4 = P(4, 32 + c);
  float4 bb2 = *(const float4*)&b2[c];
  float4 bb3 = *(const float4*)&b3[c];
  float4 o2, o3;
  o2.x = (a0.x + a1.x + a2.x + a3.x + a4.x) * 0.2f + bb2.x;
  o2.y = (a0.y + a1.y + a2.y + a3.y + a4.y) * 0.2f + bb2.y;
  o2.z = (a0.z + a1.z + a2.z + a3.z + a4.z) * 0.2f + bb2.z;
  o2.w = (a0.w + a1.w + a2.w + a3.w + a4.w) * 0.2f + bb2.w;
  o3.x = (l0.x + l1.x + l2.x + l3.x + l4.x) * 0.2f + bb3.x;
  o3.y = (l0.y + l1.y + l2.y + l3.y + l4.y) * 0.2f + bb3.y;
  o3.z = (l0.z + l1.z + l2.z + l3.z + l4.z) * 0.2f + bb3.z;
  o3.w = (l0.w + l1.w + l2.w + l3.w + l4.w) * 0.2f + bb3.w;
  *(float4*)&z_out[(size_t)n * 32 + c]  = o2;
  *(float4*)&mu_out[(size_t)n * 32 + c] = o2;
  *(float4*)&lv_out[(size_t)n * 32 + c] = o3;
}

// ---------------- launch ----------------
extern "C" void kernel_launch(void* const* d_in, const int* in_sizes, int n_in,
                              void* d_out, int out_size, void* d_ws, size_t ws_size,
                              hipStream_t stream) {
  const float* x        = (const float*)d_in[0];
  const int*   ei       = (const int*)d_in[1];
  const float* W1       = (const float*)d_in[2];
  const float* att_src1 = (const float*)d_in[3];
  const float* att_dst1 = (const float*)d_in[4];
  const float* b1       = (const float*)d_in[5];
  const float* W2       = (const float*)d_in[6];
  const float* att_src2 = (const float*)d_in[7];
  const float* att_dst2 = (const float*)d_in[8];
  const float* b2       = (const float*)d_in[9];
  const float* W3       = (const float*)d_in[10];
  const float* att_src3 = (const float*)d_in[11];
  const float* att_dst3 = (const float*)d_in[12];
  const float* b3       = (const float*)d_in[13];
  float* out = (float*)d_out;

  char* w = (char*)d_ws;
  auto alloc = [&](size_t bytes) -> void* {
    void* p = (void*)w;
    w += (bytes + 255) & ~(size_t)255;
    return p;
  };
  int*            deg    = (int*)alloc((size_t)N_NODES * 4);
  int*            offs   = (int*)alloc((size_t)(N_NODES + 1) * 4);
  int*            cursor = (int*)alloc((size_t)N_NODES * 4);
  int*            bsum   = (int*)alloc((size_t)128 * 4);
  int*            ssrc   = (int*)alloc((size_t)EP * 4);
  unsigned short* xwb    = (unsigned short*)alloc((size_t)N_NODES * 320 * 2);  // 12.8 MB
  float*          a_s    = (float*)alloc((size_t)N_NODES * 10 * 4);
  float*          a_d    = (float*)alloc((size_t)N_NODES * 10 * 4);
  unsigned short* h1b    = (unsigned short*)alloc((size_t)N_NODES * 64 * 2);   // 2.56 MB
  unsigned short* Wp1    = (unsigned short*)alloc((size_t)256 * 320 * 2);
  unsigned short* Wp23   = (unsigned short*)alloc((size_t)64 * 320 * 2);
  float*          part   = (float*)alloc((size_t)N_NODES * 320 * 4);           // 25.6 MB
  unsigned short* xbf    = (unsigned short*)part;   // ALIAS: xbf dead after gemm1,
                                                    // part written only after that
  // total ~44.4 MB (< R13-proven >=46.7 MB)

  hipMemsetAsync(deg, 0, (size_t)N_NODES * 4, stream);
  hipMemsetAsync(cursor, 0, (size_t)N_NODES * 4, stream);

  int eb = (EP + 255) / 256;
  int nb = (N_NODES + 255) / 256;   // 79
  count_deg_k<<<eb, 256, 0, stream>>>(ei, deg);
  scan1_k<<<nb, 256, 0, stream>>>(deg, offs, bsum);
  scan2_k<<<1, 128, 0, stream>>>(bsum, nb);
  scan3_k<<<nb, 256, 0, stream>>>(offs, bsum);
  scatter_k<<<eb, 256, 0, stream>>>(ei, offs, cursor, ssrc);

  int nx4 = N_NODES * 256 / 4;
  conv_bf16_k<<<(nx4 + 255) / 256, 256, 0, stream>>>((const float4*)x, (uint2*)xbf, nx4);
  packW1_k<<<(256 * 320 + 255) / 256, 256, 0, stream>>>(W1, Wp1);
  packW23_k<<<(64 * 320 + 255) / 256, 256, 0, stream>>>(W2, W3, Wp23);

  dim3 gg(5, 313);   // panel-fast: 5 panels of one A row-tile are consecutive
  int aggb = (N_NODES * HEADS + 3) / 4;   // 25000 blocks, 4 waves each, unit-major

  // ---- layer 1 ----
  mfma_gemm_k<8, 64><<<gg, 256, 0, stream>>>(xbf, Wp1, xwb,
                                             att_src1, att_dst1, nullptr, nullptr,
                                             a_s, a_d, N_NODES);
  agg1u_k<<<aggb, 256, 0, stream>>>(offs, ssrc, a_s, a_d, (const uint2*)xwb, part);
  red1_k<<<(N_NODES * 16 + 255) / 256, 256, 0, stream>>>(part, b1, h1b);

  // ---- layers 2+3 fused ----
  mfma_gemm_k<2, 32><<<gg, 256, 0, stream>>>(h1b, Wp23, xwb,
                                             att_src2, att_dst2, att_src3, att_dst3,
                                             a_s, a_d, N_NODES);
  agg23u_k<<<aggb, 256, 0, stream>>>(offs, ssrc, a_s, a_d, (const uint2*)xwb, part);
  red23_k<<<(N_NODES * 8 + 255) / 256, 256, 0, stream>>>(part, b2, b3,
                                                         out, out + (size_t)N_NODES * 32,
                                                         out + (size_t)2 * N_NODES * 32);
}

// Round 20
// 191.574 us; speedup vs baseline: 1.2032x; 1.0218x over previous
//
#include <hip/hip_runtime.h>
#include <math.h>

#define N_NODES 20000
#define N_EDGES 320000
#define EP (N_EDGES + N_NODES)   // with self loops
#define HEADS 5

typedef __attribute__((ext_vector_type(8))) __bf16 bf16x8;
typedef __attribute__((ext_vector_type(4))) float f32x4;

__device__ __forceinline__ float lrelu(float s) { return (s > 0.f) ? s : 0.2f * s; }

// fp32 -> bf16 bits, round-to-nearest-even
__device__ __forceinline__ unsigned f2bf(float f) {
  unsigned u = __float_as_uint(f);
  return (u + 0x7fffu + ((u >> 16) & 1u)) >> 16;
}

// ---------------- CSR build ----------------
__global__ void count_deg_k(const int* __restrict__ ei, int* __restrict__ deg) {
  int e = blockIdx.x * blockDim.x + threadIdx.x;
  if (e >= EP) return;
  int dst = (e < N_EDGES) ? ei[N_EDGES + e] : (e - N_EDGES);
  atomicAdd(&deg[dst], 1);
}

__global__ __launch_bounds__(256) void scan1_k(const int* __restrict__ deg,
                                               int* __restrict__ offs,
                                               int* __restrict__ bsum) {
  __shared__ int buf[256];
  int tid = threadIdx.x, i = blockIdx.x * 256 + tid;
  int v = (i < N_NODES) ? deg[i] : 0;
  buf[tid] = v;
  __syncthreads();
  for (int o = 1; o < 256; o <<= 1) {
    int t = (tid >= o) ? buf[tid - o] : 0;
    __syncthreads();
    buf[tid] += t;
    __syncthreads();
  }
  if (i < N_NODES) offs[i] = buf[tid] - v;   // block-local exclusive
  if (tid == 255) bsum[blockIdx.x] = buf[255];
}

__global__ __launch_bounds__(128) void scan2_k(int* __restrict__ bsum, int nb) {
  __shared__ int buf[128];
  int tid = threadIdx.x;
  int v = (tid < nb) ? bsum[tid] : 0;
  buf[tid] = v;
  __syncthreads();
  for (int o = 1; o < 128; o <<= 1) {
    int t = (tid >= o) ? buf[tid - o] : 0;
    __syncthreads();
    buf[tid] += t;
    __syncthreads();
  }
  if (tid < nb) bsum[tid] = buf[tid] - v;    // exclusive
}

__global__ void scan3_k(int* __restrict__ offs, const int* __restrict__ bsum) {
  int i = blockIdx.x * 256 + threadIdx.x;
  if (i < N_NODES) offs[i] += bsum[blockIdx.x];
  if (i == 0) offs[N_NODES] = EP;
}

__global__ void scatter_k(const int* __restrict__ ei, const int* __restrict__ offs,
                          int* __restrict__ cursor, int* __restrict__ ssrc) {
  int e = blockIdx.x * blockDim.x + threadIdx.x;
  if (e >= EP) return;
  int src, dst;
  if (e < N_EDGES) { src = ei[e]; dst = ei[N_EDGES + e]; }
  else             { src = e - N_EDGES; dst = src; }
  int pos = atomicAdd(&cursor[dst], 1);
  ssrc[offs[dst] + pos] = src;
}

// ---------------- fp32 -> bf16 convert (elementwise, float4 -> uint2) ----------------
__global__ __launch_bounds__(256) void conv_bf16_k(const float4* __restrict__ src,
                                                   uint2* __restrict__ dst, int n4) {
  int t = blockIdx.x * blockDim.x + threadIdx.x;
  if (t >= n4) return;
  float4 v = src[t];
  unsigned p0 = f2bf(v.x) | (f2bf(v.y) << 16);
  unsigned p1 = f2bf(v.z) | (f2bf(v.w) << 16);
  dst[t] = make_uint2(p0, p1);
}

// ---------------- pack W1[256][320] -> MFMA B-fragment order, bf16 ----------------
__global__ void packW1_k(const float* __restrict__ W, unsigned short* __restrict__ Wp) {
  int t = blockIdx.x * blockDim.x + threadIdx.x;
  if (t >= 256 * 320) return;
  int k = t / 320, n = t % 320;
  int gnt = n >> 4, ll = n & 15;
  int ks = k >> 5, kr = k & 31;
  int lh = kr >> 3, i = kr & 7;
  Wp[(((size_t)gnt * 8 + ks) * 64 + lh * 16 + ll) * 8 + i] = (unsigned short)f2bf(W[t]);
}

// ---------------- pack [W2|W3] (64x320 combined) -> fragment order, bf16 ----------------
__global__ void packW23_k(const float* __restrict__ W2, const float* __restrict__ W3,
                          unsigned short* __restrict__ Wp) {
  int t = blockIdx.x * blockDim.x + threadIdx.x;
  if (t >= 64 * 320) return;
  int k = t / 320, n = t % 320;
  int u = n / 32, c = n % 32;
  float val = (u < HEADS) ? W2[k * 160 + u * 32 + c] : W3[k * 160 + (u - HEADS) * 32 + c];
  int gnt = n >> 4, ll = n & 15;
  int ks = k >> 5, kr = k & 31;
  int lh = kr >> 3, i = kr & 7;
  Wp[(((size_t)gnt * 2 + ks) * 64 + lh * 16 + ll) * 8 + i] = (unsigned short)f2bf(val);
}

// ---------------- MFMA GEMM (bf16 in, fp32 acc) + fused att-sums ----------------
// Grid (5, 313) panel-fast. Block = 64 rows x 64 cols, 4 waves, no LDS/barriers.
template <int KSTEPS, int CH>
__global__ __launch_bounds__(256) void mfma_gemm_k(
    const unsigned short* __restrict__ A, const unsigned short* __restrict__ Bp,
    unsigned short* __restrict__ Cb,
    const float* __restrict__ attAs, const float* __restrict__ attAd,
    const float* __restrict__ attBs, const float* __restrict__ attBd,
    float* __restrict__ as_out, float* __restrict__ ad_out, int M) {
  constexpr int K = KSTEPS * 32;
  int panel = blockIdx.x;
  int bm = blockIdx.y * 64;
  int w = threadIdx.x >> 6;
  int l = threadIdx.x & 63;
  int ll = l & 15, lh = l >> 4;

  int arow = bm + w * 16 + ll;
  if (arow >= M) arow = M - 1;          // clamp; writes are guarded
  const unsigned short* ap = A + (size_t)arow * K + lh * 8;

  f32x4 acc[4] = {};
  for (int ks = 0; ks < KSTEPS; ks++) {
    bf16x8 af = *(const bf16x8*)(ap + ks * 32);
#pragma unroll
    for (int nt = 0; nt < 4; nt++) {
      bf16x8 bf = *(const bf16x8*)(Bp + (((size_t)(panel * 4 + nt) * KSTEPS + ks) * 64 + l) * 8);
      acc[nt] = __builtin_amdgcn_mfma_f32_16x16x32_bf16(af, bf, acc[nt], 0, 0, 0);
    }
  }

  int row0 = bm + w * 16 + lh * 4;
#pragma unroll
  for (int j = 0; j < 4; j++) {
    int r = row0 + j;
    if (r < M) {
#pragma unroll
      for (int nt = 0; nt < 4; nt++)
        Cb[((size_t)panel * M + r) * 64 + nt * 16 + ll] = (unsigned short)f2bf(acc[nt][j]);
    }
  }

  float ws[4], wd[4];
  if (CH == 64) {
#pragma unroll
    for (int nt = 0; nt < 4; nt++) {
      ws[nt] = attAs[panel * 64 + nt * 16 + ll];
      wd[nt] = attAd[panel * 64 + nt * 16 + ll];
    }
  } else {
#pragma unroll
    for (int nt = 0; nt < 4; nt++) {
      int u = panel * 2 + (nt >> 1);
      int c = (nt & 1) * 16 + ll;
      const float* s = (u < HEADS) ? attAs + u * 32 : attBs + (u - HEADS) * 32;
      const float* d = (u < HEADS) ? attAd + u * 32 : attBd + (u - HEADS) * 32;
      ws[nt] = s[c]; wd[nt] = d[c];
    }
  }
#pragma unroll
  for (int j = 0; j < 4; j++) {
    int r = row0 + j;
    if (CH == 64) {
      float ps = acc[0][j] * ws[0] + acc[1][j] * ws[1] + acc[2][j] * ws[2] + acc[3][j] * ws[3];
      float pd = acc[0][j] * wd[0] + acc[1][j] * wd[1] + acc[2][j] * wd[2] + acc[3][j] * wd[3];
#pragma unroll
      for (int o = 1; o < 16; o <<= 1) {
        ps += __shfl_xor(ps, o);
        pd += __shfl_xor(pd, o);
      }
      if (ll == 0 && r < M) {
        as_out[(size_t)panel * M + r] = ps;
        ad_out[(size_t)panel * M + r] = pd;
      }
    } else {
      float ls = acc[0][j] * ws[0] + acc[1][j] * ws[1];
      float ld = acc[0][j] * wd[0] + acc[1][j] * wd[1];
      float hs = acc[2][j] * ws[2] + acc[3][j] * ws[3];
      float hd = acc[2][j] * wd[2] + acc[3][j] * wd[3];
#pragma unroll
      for (int o = 1; o < 16; o <<= 1) {
        ls += __shfl_xor(ls, o); ld += __shfl_xor(ld, o);
        hs += __shfl_xor(hs, o); hd += __shfl_xor(hd, o);
      }
      if (ll == 0 && r < M) {
        int ulo = panel * 2, uhi = panel * 2 + 1;
        as_out[(size_t)ulo * M + r] = ls;  ad_out[(size_t)ulo * M + r] = ld;
        as_out[(size_t)uhi * M + r] = hs;  ad_out[(size_t)uhi * M + r] = hd;
      }
    }
  }
}

// bf16-quad load helper: uint2 -> 4 floats
__device__ __forceinline__ void bf4(uint2 v, float& f0, float& f1, float& f2, float& f3) {
  f0 = __uint_as_float(v.x << 16);
  f1 = __uint_as_float(v.x & 0xffff0000u);
  f2 = __uint_as_float(v.y << 16);
  f3 = __uint_as_float(v.y & 0xffff0000u);
}

// ---------------- layer 1 aggregate: ONE WAVE per (unit, node), UNIT-MAJOR ----------------
// R20: single 32-edge batch (8 uniform-guarded groups of 4) — for deg<=32 all
// gather loads issue in ONE batch (was two dependent 16-edge batches), removing
// the last inter-batch latency serialization. LDS alpha staging (R18),
// unit-major slices in per-XCD L2 (R19), part[u][n][64] fp32 stream-out.
__global__ __launch_bounds__(256) void agg1u_k(const int* __restrict__ offs,
                                               const int* __restrict__ ssrc,
                                               const float* __restrict__ a_s,
                                               const float* __restrict__ a_d,
                                               const uint2* __restrict__ xwb,
                                               float* __restrict__ part) {
  int wid = blockIdx.x * 4 + (threadIdx.x >> 6);
  int lane = threadIdx.x & 63;
  if (wid >= N_NODES * HEADS) return;
  int u = wid / N_NODES, n = wid - u * N_NODES;
  int w4 = threadIdx.x >> 6;
  int off = offs[n], end = offs[n + 1];
  int deg = end - off;
  float ad = a_d[(size_t)u * N_NODES + n];
  const float* asl = a_s + (size_t)u * N_NODES;
  const uint2* xb  = xwb + (size_t)u * N_NODES * 16;
  int g = lane >> 4, q = lane & 15;
  float ax = 0.f, ay = 0.f, az = 0.f, aw = 0.f;

  __shared__ uint2 eLds[4][64];

  if (deg <= 64) {
    int s = 0;
    float e = -1e30f;
    if (lane < deg) { s = ssrc[off + lane]; e = lrelu(asl[s] + ad); }
    float m = e;
#pragma unroll
    for (int o = 32; o > 0; o >>= 1) m = fmaxf(m, __shfl_xor(m, o));
    float p = (lane < deg) ? __expf(e - m) : 0.f;
    float den = p;
#pragma unroll
    for (int o = 32; o > 0; o >>= 1) den += __shfl_xor(den, o);
    float alpha = p * (1.f / (den + 1e-16f));   // 0 for tail lanes

    eLds[w4][lane] = make_uint2(__float_as_uint(alpha), (unsigned)s);

    for (int base = 0; base < deg; base += 32) {
      float alv[8];
      uint2 v[8];
#pragma unroll
      for (int t = 0; t < 8; t++) {
        int b4 = base + t * 4;
        if (b4 < deg) {                        // wave-uniform guard
          uint2 es = eLds[w4][b4 + g];         // broadcast within group
          alv[t] = __uint_as_float(es.x);
          v[t] = xb[(size_t)es.y * 16 + q];
        }
      }
#pragma unroll
      for (int t = 0; t < 8; t++) {
        if (base + t * 4 < deg) {
          float f0, f1, f2, f3;
          bf4(v[t], f0, f1, f2, f3);
          ax += alv[t] * f0; ay += alv[t] * f1;
          az += alv[t] * f2; aw += alv[t] * f3;
        }
      }
    }
  } else {
    float m = -1e30f;
    for (int i = off + lane; i < end; i += 64) m = fmaxf(m, lrelu(asl[ssrc[i]] + ad));
#pragma unroll
    for (int o = 32; o > 0; o >>= 1) m = fmaxf(m, __shfl_xor(m, o));
    float den = 0.f;
    for (int i = off + lane; i < end; i += 64) den += __expf(lrelu(asl[ssrc[i]] + ad) - m);
#pragma unroll
    for (int o = 32; o > 0; o >>= 1) den += __shfl_xor(den, o);
    float inv = 1.f / (den + 1e-16f);
    for (int base = off; base < end; base += 4) {
      int e = base + g;
      if (e < end) {
        int sv = ssrc[e];
        float al = __expf(lrelu(asl[sv] + ad) - m) * inv;
        float f0, f1, f2, f3;
        bf4(xb[(size_t)sv * 16 + q], f0, f1, f2, f3);
        ax += al * f0; ay += al * f1; az += al * f2; aw += al * f3;
      }
    }
  }

#pragma unroll
  for (int o = 16; o < 64; o <<= 1) {
    ax += __shfl_xor(ax, o); ay += __shfl_xor(ay, o);
    az += __shfl_xor(az, o); aw += __shfl_xor(aw, o);
  }
  if (g == 0)
    *(float4*)&part[((size_t)u * N_NODES + n) * 64 + q * 4] =
        make_float4(ax, ay, az, aw);
}

// ---------------- layer-1 reduce: mean over heads + bias + relu -> h1 bf16 ----------------
__global__ __launch_bounds__(256) void red1_k(const float* __restrict__ part,
                                              const float* __restrict__ b1,
                                              unsigned short* __restrict__ h1b) {
  int t = blockIdx.x * blockDim.x + threadIdx.x;   // n*16 + q
  if (t >= N_NODES * 16) return;
  int n = t >> 4, q = t & 15;
  float x = 0.f, y = 0.f, z = 0.f, w = 0.f;
#pragma unroll
  for (int h = 0; h < HEADS; h++) {
    float4 v = *(const float4*)&part[((size_t)h * N_NODES + n) * 64 + q * 4];
    x += v.x; y += v.y; z += v.z; w += v.w;
  }
  float4 bb = *(const float4*)&b1[q * 4];
  unsigned short r0 = (unsigned short)f2bf(fmaxf(x * 0.2f + bb.x, 0.f));
  unsigned short r1 = (unsigned short)f2bf(fmaxf(y * 0.2f + bb.y, 0.f));
  unsigned short r2 = (unsigned short)f2bf(fmaxf(z * 0.2f + bb.z, 0.f));
  unsigned short r3 = (unsigned short)f2bf(fmaxf(w * 0.2f + bb.w, 0.f));
  unsigned p0 = (unsigned)r0 | ((unsigned)r1 << 16);
  unsigned p1 = (unsigned)r2 | ((unsigned)r3 << 16);
  *(uint2*)&h1b[(size_t)n * 64 + q * 4] = make_uint2(p0, p1);
}

// ---------------- layers 2+3 aggregate: ONE WAVE per (pair, node), UNIT-MAJOR ----------------
__global__ __launch_bounds__(256) void agg23u_k(const int* __restrict__ offs,
                                                const int* __restrict__ ssrc,
                                                const float* __restrict__ a_s,
                                                const float* __restrict__ a_d,
                                                const uint2* __restrict__ xwb,
                                                float* __restrict__ part) {
  int wid = blockIdx.x * 4 + (threadIdx.x >> 6);
  int lane = threadIdx.x & 63;
  if (wid >= N_NODES * HEADS) return;
  int gp = wid / N_NODES, n = wid - gp * N_NODES;
  int w4 = threadIdx.x >> 6;
  int ulo = 2 * gp, uhi = 2 * gp + 1;
  int off = offs[n], end = offs[n + 1];
  int deg = end - off;
  float adlo = a_d[(size_t)ulo * N_NODES + n];
  float adhi = a_d[(size_t)uhi * N_NODES + n];
  const float* aslo = a_s + (size_t)ulo * N_NODES;
  const float* ashi = a_s + (size_t)uhi * N_NODES;
  const uint2* xb   = xwb + (size_t)gp * N_NODES * 16;
  int g = lane >> 4, q = lane & 15;
  float ax = 0.f, ay = 0.f, az = 0.f, aw = 0.f;

  __shared__ uint4 eLds[4][64];

  if (deg <= 64) {
    int s = 0;
    float elo = -1e30f, ehi = -1e30f;
    if (lane < deg) {
      s = ssrc[off + lane];
      elo = lrelu(aslo[s] + adlo);
      ehi = lrelu(ashi[s] + adhi);
    }
    float mlo = elo, mhi = ehi;
#pragma unroll
    for (int o = 32; o > 0; o >>= 1) {
      mlo = fmaxf(mlo, __shfl_xor(mlo, o));
      mhi = fmaxf(mhi, __shfl_xor(mhi, o));
    }
    float plo = (lane < deg) ? __expf(elo - mlo) : 0.f;
    float phi = (lane < deg) ? __expf(ehi - mhi) : 0.f;
    float dlo = plo, dhi = phi;
#pragma unroll
    for (int o = 32; o > 0; o >>= 1) {
      dlo += __shfl_xor(dlo, o);
      dhi += __shfl_xor(dhi, o);
    }
    float allo = plo * (1.f / (dlo + 1e-16f));   // 0 for tail lanes
    float alhi = phi * (1.f / (dhi + 1e-16f));

    eLds[w4][lane] = make_uint4(__float_as_uint(allo), __float_as_uint(alhi),
                                (unsigned)s, 0u);

    for (int base = 0; base < deg; base += 32) {
      float alv[8];
      uint2 v[8];
#pragma unroll
      for (int t = 0; t < 8; t++) {
        int b4 = base + t * 4;
        if (b4 < deg) {                        // wave-uniform guard
          uint4 es = eLds[w4][b4 + g];         // broadcast within group
          alv[t] = __uint_as_float((q < 8) ? es.x : es.y);
          v[t] = xb[(size_t)es.z * 16 + q];
        }
      }
#pragma unroll
      for (int t = 0; t < 8; t++) {
        if (base + t * 4 < deg) {
          float f0, f1, f2, f3;
          bf4(v[t], f0, f1, f2, f3);
          ax += alv[t] * f0; ay += alv[t] * f1;
          az += alv[t] * f2; aw += alv[t] * f3;
        }
      }
    }
  } else {
    float mlo = -1e30f, mhi = -1e30f;
    for (int i = off + lane; i < end; i += 64) {
      int sv = ssrc[i];
      mlo = fmaxf(mlo, lrelu(aslo[sv] + adlo));
      mhi = fmaxf(mhi, lrelu(ashi[sv] + adhi));
    }
#pragma unroll
    for (int o = 32; o > 0; o >>= 1) {
      mlo = fmaxf(mlo, __shfl_xor(mlo, o));
      mhi = fmaxf(mhi, __shfl_xor(mhi, o));
    }
    float dlo = 0.f, dhi = 0.f;
    for (int i = off + lane; i < end; i += 64) {
      int sv = ssrc[i];
      dlo += __expf(lrelu(aslo[sv] + adlo) - mlo);
      dhi += __expf(lrelu(ashi[sv] + adhi) - mhi);
    }
#pragma unroll
    for (int o = 32; o > 0; o >>= 1) {
      dlo += __shfl_xor(dlo, o);
      dhi += __shfl_xor(dhi, o);
    }
    float ilo = 1.f / (dlo + 1e-16f), ihi = 1.f / (dhi + 1e-16f);
    for (int base = off; base < end; base += 4) {
      int e = base + g;
      if (e < end) {
        int sv = ssrc[e];
        float al;
        if (q < 8) al = __expf(lrelu(aslo[sv] + adlo) - mlo) * ilo;
        else       al = __expf(lrelu(ashi[sv] + adhi) - mhi) * ihi;
        float f0, f1, f2, f3;
        bf4(xb[(size_t)sv * 16 + q], f0, f1, f2, f3);
        ax += al * f0; ay += al * f1; az += al * f2; aw += al * f3;
      }
    }
  }

#pragma unroll
  for (int o = 16; o < 64; o <<= 1) {
    ax += __shfl_xor(ax, o); ay += __shfl_xor(ay, o);
    az += __shfl_xor(az, o); aw += __shfl_xor(aw, o);
  }
  if (g == 0)
    *(float4*)&part[((size_t)gp * N_NODES + n) * 64 + q * 4] =
        make_float4(ax, ay, az, aw);
}

// ---------------- layers 2+3 reduce: combine pairs -> z, mu, logvar ----------------
__global__ __launch_bounds__(256) void red23_k(const float* __restrict__ part,
                                               const float* __restrict__ b2,
                                               const float* __restrict__ b3,
                                               float* __restrict__ z_out,
                                               float* __restrict__ mu_out,
                                               float* __restrict__ lv_out) {
  int t = blockIdx.x * blockDim.x + threadIdx.x;   // n*8 + q
  if (t >= N_NODES * 8) return;
  int n = t >> 3, q = t & 7;
  int c = q * 4;
  auto P = [&](int g, int j) -> float4 {
    return *(const float4*)&part[((size_t)g * N_NODES + n) * 64 + j];
  };
  float4 a0 = P(0, c), a1 = P(0, 32 + c), a2 = P(1, c), a3 = P(1, 32 + c), a4 = P(2, c);
  float4 l0 = P(2, 32 + c), l1 = P(3, c), l2 = P(3, 32 + c), l3 = P(4, c), l4 = P(4, 32 + c);
  float4 bb2 = *(const float4*)&b2[c];
  float4 bb3 = *(const float4*)&b3[c];
  float4 o2, o3;
  o2.x = (a0.x + a1.x + a2.x + a3.x + a4.x) * 0.2f + bb2.x;
  o2.y = (a0.y + a1.y + a2.y + a3.y + a4.y) * 0.2f + bb2.y;
  o2.z = (a0.z + a1.z + a2.z + a3.z + a4.z) * 0.2f + bb2.z;
  o2.w = (a0.w + a1.w + a2.w + a3.w + a4.w) * 0.2f + bb2.w;
  o3.x = (l0.x + l1.x + l2.x + l3.x + l4.x) * 0.2f + bb3.x;
  o3.y = (l0.y + l1.y + l2.y + l3.y + l4.y) * 0.2f + bb3.y;
  o3.z = (l0.z + l1.z + l2.z + l3.z + l4.z) * 0.2f + bb3.z;
  o3.w = (l0.w + l1.w + l2.w + l3.w + l4.w) * 0.2f + bb3.w;
  *(float4*)&z_out[(size_t)n * 32 + c]  = o2;
  *(float4*)&mu_out[(size_t)n * 32 + c] = o2;
  *(float4*)&lv_out[(size_t)n * 32 + c] = o3;
}

// ---------------- launch ----------------
extern "C" void kernel_launch(void* const* d_in, const int* in_sizes, int n_in,
                              void* d_out, int out_size, void* d_ws, size_t ws_size,
                              hipStream_t stream) {
  const float* x        = (const float*)d_in[0];
  const int*   ei       = (const int*)d_in[1];
  const float* W1       = (const float*)d_in[2];
  const float* att_src1 = (const float*)d_in[3];
  const float* att_dst1 = (const float*)d_in[4];
  const float* b1       = (const float*)d_in[5];
  const float* W2       = (const float*)d_in[6];
  const float* att_src2 = (const float*)d_in[7];
  const float* att_dst2 = (const float*)d_in[8];
  const float* b2       = (const float*)d_in[9];
  const float* W3       = (const float*)d_in[10];
  const float* att_src3 = (const float*)d_in[11];
  const float* att_dst3 = (const float*)d_in[12];
  const float* b3       = (const float*)d_in[13];
  float* out = (float*)d_out;

  char* w = (char*)d_ws;
  auto alloc = [&](size_t bytes) -> void* {
    void* p = (void*)w;
    w += (bytes + 255) & ~(size_t)255;
    return p;
  };
  int*            deg    = (int*)alloc((size_t)N_NODES * 4);
  int*            offs   = (int*)alloc((size_t)(N_NODES + 1) * 4);
  int*            cursor = (int*)alloc((size_t)N_NODES * 4);
  int*            bsum   = (int*)alloc((size_t)128 * 4);
  int*            ssrc   = (int*)alloc((size_t)EP * 4);
  unsigned short* xwb    = (unsigned short*)alloc((size_t)N_NODES * 320 * 2);  // 12.8 MB
  float*          a_s    = (float*)alloc((size_t)N_NODES * 10 * 4);
  float*          a_d    = (float*)alloc((size_t)N_NODES * 10 * 4);
  unsigned short* h1b    = (unsigned short*)alloc((size_t)N_NODES * 64 * 2);   // 2.56 MB
  unsigned short* Wp1    = (unsigned short*)alloc((size_t)256 * 320 * 2);
  unsigned short* Wp23   = (unsigned short*)alloc((size_t)64 * 320 * 2);
  float*          part   = (float*)alloc((size_t)N_NODES * 320 * 4);           // 25.6 MB
  unsigned short* xbf    = (unsigned short*)part;   // ALIAS: xbf dead after gemm1
  // total ~44.4 MB (proven R19)

  hipMemsetAsync(deg, 0, (size_t)N_NODES * 4, stream);
  hipMemsetAsync(cursor, 0, (size_t)N_NODES * 4, stream);

  int eb = (EP + 255) / 256;
  int nb = (N_NODES + 255) / 256;   // 79
  count_deg_k<<<eb, 256, 0, stream>>>(ei, deg);
  scan1_k<<<nb, 256, 0, stream>>>(deg, offs, bsum);
  scan2_k<<<1, 128, 0, stream>>>(bsum, nb);
  scan3_k<<<nb, 256, 0, stream>>>(offs, bsum);
  scatter_k<<<eb, 256, 0, stream>>>(ei, offs, cursor, ssrc);

  int nx4 = N_NODES * 256 / 4;
  conv_bf16_k<<<(nx4 + 255) / 256, 256, 0, stream>>>((const float4*)x, (uint2*)xbf, nx4);
  packW1_k<<<(256 * 320 + 255) / 256, 256, 0, stream>>>(W1, Wp1);
  packW23_k<<<(64 * 320 + 255) / 256, 256, 0, stream>>>(W2, W3, Wp23);

  dim3 gg(5, 313);   // panel-fast: 5 panels of one A row-tile are consecutive
  int aggb = (N_NODES * HEADS + 3) / 4;   // 25000 blocks, 4 waves each, unit-major

  // ---- layer 1 ----
  mfma_gemm_k<8, 64><<<gg, 256, 0, stream>>>(xbf, Wp1, xwb,
                                             att_src1, att_dst1, nullptr, nullptr,
                                             a_s, a_d, N_NODES);
  agg1u_k<<<aggb, 256, 0, stream>>>(offs, ssrc, a_s, a_d, (const uint2*)xwb, part);
  red1_k<<<(N_NODES * 16 + 255) / 256, 256, 0, stream>>>(part, b1, h1b);

  // ---- layers 2+3 fused ----
  mfma_gemm_k<2, 32><<<gg, 256, 0, stream>>>(h1b, Wp23, xwb,
                                             att_src2, att_dst2, att_src3, att_dst3,
                                             a_s, a_d, N_NODES);
  agg23u_k<<<aggb, 256, 0, stream>>>(offs, ssrc, a_s, a_d, (const uint2*)xwb, part);
  red23_k<<<(N_NODES * 8 + 255) / 256, 256, 0, stream>>>(part, b2, b3,
                                                         out, out + (size_t)N_NODES * 32,
                                                         out + (size_t)2 * N_NODES * 32);
}